// Round 3
// baseline (4271.986 us; speedup 1.0000x reference)
//
#include <hip/hip_runtime.h>
#include <math.h>
#include <stdint.h>

#define NB 8
#define CIN 512
#define HW 4096
#define ANUM 9
#define NANC 36864
#define PRE 2000
#define POST 300

// d_out float offsets
#define OUT_LOCS   0
#define OUT_SCORES 1179648
#define OUT_ROIS   1769472
#define OUT_RIDX   1779072
#define OUT_ANC    1781472

// ---------------- K0: anchors ----------------
__global__ void anchor_kernel(float* __restrict__ out) {
  int i = blockIdx.x * 256 + threadIdx.x;
  if (i >= NANC) return;
  int s = i / 9, a = i - s * 9;
  int y = s >> 6, x = s & 63;
  int ri = a / 3, si = a - ri * 3;
  double r = (ri == 0) ? 0.5 : (ri == 1 ? 1.0 : 2.0);
  double sc = (si == 0) ? 8.0 : (si == 1 ? 16.0 : 32.0);
  double hh = 16.0 * sc * sqrt(r);
  double ww = 16.0 * sc * sqrt(1.0 / r);
  float a0 = (float)(8.0 - hh * 0.5);
  float a1 = (float)(8.0 - ww * 0.5);
  float a2 = (float)(8.0 + hh * 0.5);
  float a3 = (float)(8.0 + ww * 0.5);
  float sy = (float)(y * 16), sx = (float)(x * 16);
  out[OUT_ANC + i * 4 + 0] = a0 + sy;
  out[OUT_ANC + i * 4 + 1] = a1 + sx;
  out[OUT_ANC + i * 4 + 2] = a2 + sy;
  out[OUT_ANC + i * 4 + 3] = a3 + sx;
}

// ---------------- K0b: weight transpose w[oc][ic][k] -> wT[ic][k][oc] ----------------
__global__ void wt_kernel(const float* __restrict__ w, float* __restrict__ wT) {
  int i = blockIdx.x * 256 + threadIdx.x;
  if (i >= CIN * 9 * CIN) return;
  int oc = i & 511;
  int rem = i >> 9;
  int k = rem % 9;
  int ic = rem / 9;
  wT[i] = w[((size_t)oc * CIN + ic) * 9 + k];
}

// ---------------- K1: conv3x3 + bias + relu ----------------
// v3: launch_bounds(256,2) -> 256-VGPR cap (kill AGPR shuttle); hoisted staging addresses.
// grid 1024: ocb(32) fastest, tile(4), n(8). 256 thr: rows{2ty,2ty+1}, cols{tx,tx+16}
__global__ __launch_bounds__(256, 2) void conv3_v3(
    const float* __restrict__ x, const float* __restrict__ wT,
    const float* __restrict__ bias, float* __restrict__ h) {
  __shared__ float xs[4][34][40];  // row stride 40 -> 2-way on reads (free)
  float* xsf = &xs[0][0][0];
  int blk = blockIdx.x;
  int ocb = blk & 31;
  int t = (blk >> 5) & 3;
  int n = blk >> 7;
  int ty0 = (t >> 1) * 32, tx0 = (t & 1) * 32;
  int tid = threadIdx.x;
  int ty = tid >> 4;
  int tx = tid & 15;

  // ---- hoisted staging addresses (invariant over ic0) ----
  int goffs[19];  // element offset into xb (ic*HW + gy*64 + gx), -1 if OOB/pad
  int laddrs[19]; // flat LDS float index, -1 if slot inactive
#pragma unroll
  for (int s = 0; s < 19; ++s) {
    int l = tid + s * 256;
    int ic = l / 1156; int rem = l - ic * 1156;
    int dy = rem / 34; int dx = rem - dy * 34;
    int gy = ty0 - 1 + dy, gx = tx0 - 1 + dx;
    bool active = (l < 4624);
    bool inb = active && ((unsigned)gy < 64u) && ((unsigned)gx < 64u);
    goffs[s] = inb ? (ic * HW + (gy << 6) + gx) : -1;
    laddrs[s] = active ? (ic * 1360 + dy * 40 + dx) : -1;
  }

  float acc[16][4];
#pragma unroll
  for (int o = 0; o < 16; o++)
#pragma unroll
    for (int p = 0; p < 4; p++) acc[o][p] = 0.f;

  const float* xn = x + (size_t)n * CIN * HW;
  const float* wb = wT + (ocb << 4);

#pragma unroll 1
  for (int ic0 = 0; ic0 < CIN; ic0 += 4) {
    const float* xb = xn + (size_t)ic0 * HW;
#pragma unroll
    for (int s = 0; s < 19; ++s) {
      if (laddrs[s] >= 0) {
        float v = 0.f;
        if (goffs[s] >= 0) v = xb[goffs[s]];
        xsf[laddrs[s]] = v;
      }
    }
    __syncthreads();
#pragma unroll 1
    for (int ic = 0; ic < 4; ++ic) {
      float xv[4][6];
#pragma unroll
      for (int r = 0; r < 4; ++r) {
#pragma unroll
        for (int c = 0; c < 3; ++c) {
          xv[r][c]     = xs[ic][2 * ty + r][tx + c];
          xv[r][3 + c] = xs[ic][2 * ty + r][tx + 16 + c];
        }
      }
      const float* wic = wb + (size_t)(ic0 + ic) * 9 * 512;
#pragma unroll
      for (int k = 0; k < 9; ++k) {
        int ky = k / 3, kx = k - ky * 3;
        const float4* wk = (const float4*)(wic + (k << 9));
        float4 w0 = wk[0], w1 = wk[1], w2 = wk[2], w3 = wk[3];
        float wv[16] = {w0.x, w0.y, w0.z, w0.w, w1.x, w1.y, w1.z, w1.w,
                        w2.x, w2.y, w2.z, w2.w, w3.x, w3.y, w3.z, w3.w};
#pragma unroll
        for (int o = 0; o < 16; ++o)
#pragma unroll
          for (int p = 0; p < 2; ++p)
#pragma unroll
            for (int q = 0; q < 2; ++q)
              acc[o][p * 2 + q] = fmaf(xv[p + ky][q * 3 + kx], wv[o], acc[o][p * 2 + q]);
      }
    }
    __syncthreads();
  }
#pragma unroll
  for (int o = 0; o < 16; o++) {
    int oc = ocb * 16 + o;
    float bv = bias[oc];
#pragma unroll
    for (int p = 0; p < 2; p++)
#pragma unroll
      for (int q = 0; q < 2; q++) {
        int gy = ty0 + 2 * ty + p, gx = tx0 + tx + 16 * q;
        float v = acc[o][p * 2 + q] + bv;
        h[((size_t)n * CIN + oc) * HW + gy * 64 + gx] = v > 0.f ? v : 0.f;
      }
  }
}

// ---------------- K2: 1x1 heads + transpose + fg + box decode ----------------
__global__ __launch_bounds__(256) void heads_kernel(
    const float* __restrict__ h, const float* __restrict__ sw,
    const float* __restrict__ sb, const float* __restrict__ lw,
    const float* __restrict__ lb, float* __restrict__ out,
    float* __restrict__ fgm, float* __restrict__ boxes) {
  __shared__ float wlds[2][64][56];
  __shared__ float part[128][56];
  int tid = threadIdx.x;
  int sl = tid >> 7;
  int pl = tid & 127;
  int blk = blockIdx.x;
  int n = blk >> 5;
  int s0 = (blk & 31) * 128;

  float acc[54];
#pragma unroll
  for (int k = 0; k < 54; k++) acc[k] = 0.f;

  for (int cc = 0; cc < 256; cc += 64) {
    for (int l = tid; l < 2 * 64 * 54; l += 256) {
      int slc = l / (64 * 54); int rem = l - slc * 64 * 54;
      int cl = rem / 54; int k = rem - cl * 54;
      int c = slc * 256 + cc + cl;
      wlds[slc][cl][k] = (k < 18) ? sw[k * CIN + c] : lw[(k - 18) * CIN + c];
    }
    __syncthreads();
    int cbase = sl * 256 + cc;
    for (int cl = 0; cl < 64; ++cl) {
      float hv = h[((size_t)n * CIN + cbase + cl) * HW + s0 + pl];
#pragma unroll
      for (int k = 0; k < 54; ++k) acc[k] = fmaf(hv, wlds[sl][cl][k], acc[k]);
    }
    __syncthreads();
  }
  if (sl == 1) {
#pragma unroll
    for (int k = 0; k < 54; k++) part[pl][k] = acc[k];
  }
  __syncthreads();
  if (sl == 0) {
#pragma unroll
    for (int k = 0; k < 54; k++) acc[k] += part[pl][k];
    int s = s0 + pl;
    int y = s >> 6, xx = s & 63;
    float sc[18], lo[36];
#pragma unroll
    for (int k = 0; k < 18; k++) sc[k] = acc[k] + sb[k];
#pragma unroll
    for (int k = 0; k < 36; k++) lo[k] = acc[18 + k] + lb[k];
    size_t base = (size_t)n * NANC + (size_t)s * 9;
#pragma unroll
    for (int i = 0; i < 36; i++) out[OUT_LOCS + base * 4 + i] = lo[i];
#pragma unroll
    for (int i = 0; i < 18; i++) out[OUT_SCORES + base * 2 + i] = sc[i];
    float syf = (float)(y * 16), sxf = (float)(xx * 16);
#pragma unroll
    for (int a = 0; a < 9; a++) {
      float s0v = sc[a * 2], s1v = sc[a * 2 + 1];
      float m = fmaxf(s0v, s1v);
      float e0 = expf(s0v - m), e1 = expf(s1v - m);
      float fg = e1 / (e0 + e1);
      int ri = a / 3, si = a - ri * 3;
      double r = (ri == 0) ? 0.5 : (ri == 1 ? 1.0 : 2.0);
      double scd = (si == 0) ? 8.0 : (si == 1 ? 16.0 : 32.0);
      double hhd = 16.0 * scd * sqrt(r);
      double wwd = 16.0 * scd * sqrt(1.0 / r);
      float a0 = (float)(8.0 - hhd * 0.5) + syf;
      float a1 = (float)(8.0 - wwd * 0.5) + sxf;
      float a2 = (float)(8.0 + hhd * 0.5) + syf;
      float a3 = (float)(8.0 + wwd * 0.5) + sxf;
      float hA = a2 - a0, wA = a3 - a1;
      float cy = a0 + 0.5f * hA, cx = a1 + 0.5f * wA;
      float dy = lo[a * 4 + 0], dx = lo[a * 4 + 1];
      float dh = lo[a * 4 + 2], dw = lo[a * 4 + 3];
      float cy2 = dy * hA + cy, cx2 = dx * wA + cx;
      float h2 = expf(dh) * hA, w2 = expf(dw) * wA;
      float b0 = cy2 - 0.5f * h2, b1 = cx2 - 0.5f * w2;
      float b2 = cy2 + 0.5f * h2, b3 = cx2 + 0.5f * w2;
      b0 = fminf(fmaxf(b0, 0.f), 1024.f);
      b1 = fminf(fmaxf(b1, 0.f), 1024.f);
      b2 = fminf(fmaxf(b2, 0.f), 1024.f);
      b3 = fminf(fmaxf(b3, 0.f), 1024.f);
      float hs = b2 - b0, wss = b3 - b1;
      bool valid = (hs >= 16.f) && (wss >= 16.f);
      size_t bi = base + a;
      boxes[bi * 4 + 0] = b0; boxes[bi * 4 + 1] = b1;
      boxes[bi * 4 + 2] = b2; boxes[bi * 4 + 3] = b3;
      fgm[bi] = valid ? fg : -__builtin_inff();
    }
  }
}

// ---------------- K3: top-2000 (4-pass radix on 32-bit orderable score) ----------------
__device__ __forceinline__ uint32_t ord32(float v) {
  uint32_t s = __float_as_uint(v);
  return (s & 0x80000000u) ? ~s : (s | 0x80000000u);
}

__global__ __launch_bounds__(1024) void select2_kernel(
    const float* __restrict__ fgm, const float* __restrict__ boxes,
    float4* __restrict__ selb, uint8_t* __restrict__ selv) {
  int n = blockIdx.x;
  const float* f = fgm + (size_t)n * NANC;
  __shared__ uint32_t hist[256];
  __shared__ uint32_t segsum[16], segsufE[16];
  __shared__ uint64_t keys[2048];
  __shared__ uint32_t sh_digit, sh_T, scnt;
  int tid = threadIdx.x;
  uint32_t pref = 0;
  uint32_t T = PRE;
  for (int p = 0; p < 4; ++p) {
    int shift = 24 - 8 * p;
    if (tid < 256) hist[tid] = 0;
    __syncthreads();
    for (int i = tid; i < NANC; i += 1024) {
      uint32_t u = ord32(f[i]);
      bool match = (p == 0) || ((u >> (shift + 8)) == (pref >> (shift + 8)));
      if (match) atomicAdd(&hist[(u >> shift) & 255u], 1u);
    }
    __syncthreads();
    if (tid < 16) {
      uint32_t s = 0;
      for (int j = 0; j < 16; ++j) s += hist[tid * 16 + j];
      segsum[tid] = s;
    }
    __syncthreads();
    if (tid == 0) {
      uint32_t run = 0;
      for (int s = 15; s >= 0; --s) { segsufE[s] = run; run += segsum[s]; }
    }
    __syncthreads();
    if (tid < 256) {
      int d = tid, s = d >> 4;
      uint32_t loc = 0;
      for (int j = d; j < (s + 1) * 16; ++j) loc += hist[j];
      uint32_t suf = segsufE[s] + loc;
      uint32_t sufn = suf - hist[d];
      if (suf >= T && sufn < T) { sh_digit = (uint32_t)d; sh_T = T - sufn; }
    }
    __syncthreads();
    pref |= sh_digit << shift;
    T = sh_T;
    __syncthreads();
  }
  if (tid == 0) scnt = 0;
  __syncthreads();
  for (int i = tid; i < NANC; i += 1024) {
    uint32_t u = ord32(f[i]);
    if (u >= pref) {
      uint32_t pos = atomicAdd(&scnt, 1u);
      if (pos < 2048) keys[pos] = ((uint64_t)u << 32) | (uint32_t)(~(uint32_t)i);
    }
  }
  __syncthreads();
  uint32_t sc = scnt > 2048 ? 2048 : scnt;
  for (int i = sc + tid; i < 2048; i += 1024) keys[i] = 0;
  __syncthreads();
  for (int k = 2; k <= 2048; k <<= 1) {
    for (int j = k >> 1; j > 0; j >>= 1) {
      for (int e = tid; e < 2048; e += 1024) {
        int partner = e ^ j;
        if (partner > e) {
          bool up = ((e & k) == 0);
          uint64_t a = keys[e], b = keys[partner];
          if (up ? (a < b) : (a > b)) { keys[e] = b; keys[partner] = a; }
        }
      }
      __syncthreads();
    }
  }
  for (int t2 = tid; t2 < PRE; t2 += 1024) {
    uint64_t key = keys[t2];
    uint32_t idx = ~((uint32_t)(key & 0xFFFFFFFFu));
    const float4* bp = (const float4*)(boxes + ((size_t)n * NANC + idx) * 4);
    selb[(size_t)n * 2048 + t2] = *bp;
    selv[(size_t)n * 2048 + t2] = ((uint32_t)(key >> 32)) > 0x007FFFFFu ? 1 : 0;
  }
}

// ---------------- K4a: NMS suppression mask (grid-parallel) ----------------
// grid 2000 = 8 n * 250; block 256 = 8 i-rows x 32 j-words
__global__ __launch_bounds__(256) void nms_mask_kernel(
    const float4* __restrict__ selb, uint64_t* __restrict__ mask) {
  __shared__ float by0[PRE], bx0_[PRE], by1[PRE], bx1_[PRE], bar[PRE];
  int b = blockIdx.x;
  int n = b / 250;
  int i0 = (b % 250) * 8;
  int tid = threadIdx.x;
  for (int j = tid; j < PRE; j += 256) {
    float4 bb = selb[(size_t)n * 2048 + j];
    by0[j] = bb.x; bx0_[j] = bb.y; by1[j] = bb.z; bx1_[j] = bb.w;
    bar[j] = (bb.z - bb.x) * (bb.w - bb.y);
  }
  __syncthreads();
  int i = i0 + (tid >> 5);
  int jw = tid & 31;
  float iy0 = by0[i], ix0 = bx0_[i], iy1 = by1[i], ix1 = bx1_[i], ia = bar[i];
  uint64_t bits = 0;
  int jb = jw * 64;
  for (int tb = 0; tb < 64; ++tb) {
    int tbp = (tb + jw) & 63;  // swizzle to avoid 64-way LDS bank conflicts
    int j = jb + tbp;
    if (j < PRE && j > i) {
      float ty = fmaxf(iy0, by0[j]);
      float txx = fmaxf(ix0, bx0_[j]);
      float byv = fminf(iy1, by1[j]);
      float bxv = fminf(ix1, bx1_[j]);
      float ih = byv - ty; if (ih < 0.f) ih = 0.f;
      float iw = bxv - txx; if (iw < 0.f) iw = 0.f;
      float inter = ih * iw;
      float iou = inter / (ia + bar[j] - inter + 1e-9f);
      if (iou > 0.7f) bits |= (1ull << tbp);
    }
  }
  mask[((size_t)n * PRE + i) * 32 + jw] = bits;
}

// ---------------- K4b: serial bit-scan NMS + write rois (1 wave / image) ----------------
__global__ __launch_bounds__(64) void nms_scan_kernel(
    const uint8_t* __restrict__ selv, const uint64_t* __restrict__ mask,
    const float4* __restrict__ selb, float* __restrict__ out) {
  int n = blockIdx.x;
  int lane = threadIdx.x;
  const uint8_t* sv = selv + (size_t)n * 2048;
  uint64_t kw = 0;
  for (int wblk = 0; wblk < 32; ++wblk) {
    int j = wblk * 64 + lane;
    bool pred = (j < PRE) && (sv[j] != 0);
    uint64_t m = __ballot(pred);
    if (lane == wblk) kw = m;
  }
  const uint64_t* mrow = mask + (size_t)n * PRE * 32;
  for (int i0 = 0; i0 < PRE; i0 += 16) {
    uint64_t rr[16];
#pragma unroll
    for (int tt = 0; tt < 16; ++tt)
      rr[tt] = (lane < 32) ? mrow[(size_t)(i0 + tt) * 32 + lane] : 0;
#pragma unroll
    for (int tt = 0; tt < 16; ++tt) {
      int i = i0 + tt;
      uint64_t w = __shfl(kw, i >> 6);
      if ((w >> (i & 63)) & 1ull) kw &= ~rr[tt];
    }
  }
  uint64_t kwv = (lane < 32) ? kw : 0ull;
  int pc = __popcll(kwv);
  int pre = pc;
  for (int d = 1; d < 64; d <<= 1) {
    int v = __shfl_up(pre, d);
    if (lane >= d) pre += v;
  }
  int total = __shfl(pre, 63);
  int rank = pre - pc;
  uint64_t bits = kwv;
  while (bits) {
    int bpos = __ffsll((unsigned long long)bits) - 1;
    bits &= bits - 1;
    if (rank < POST) {
      int j = lane * 64 + bpos;
      float4 bx = selb[(size_t)n * 2048 + j];
      size_t o = (size_t)OUT_ROIS + ((size_t)n * POST + rank) * 4;
      out[o + 0] = bx.x; out[o + 1] = bx.y; out[o + 2] = bx.z; out[o + 3] = bx.w;
    }
    rank++;
  }
  int cnt = total > POST ? POST : total;
  for (int r2 = cnt + lane; r2 < POST; r2 += 64) {
    size_t o = (size_t)OUT_ROIS + ((size_t)n * POST + r2) * 4;
    out[o + 0] = 0.f; out[o + 1] = 0.f; out[o + 2] = 0.f; out[o + 3] = 0.f;
  }
  for (int r2 = lane; r2 < POST; r2 += 64)
    out[OUT_RIDX + n * POST + r2] = (float)n;
}

extern "C" void kernel_launch(void* const* d_in, const int* in_sizes, int n_in,
                              void* d_out, int out_size, void* d_ws, size_t ws_size,
                              hipStream_t stream) {
  const float* x   = (const float*)d_in[0];
  const float* c1w = (const float*)d_in[1];
  const float* c1b = (const float*)d_in[2];
  const float* sw  = (const float*)d_in[3];
  const float* sb  = (const float*)d_in[4];
  const float* lw  = (const float*)d_in[5];
  const float* lb  = (const float*)d_in[6];
  float* out = (float*)d_out;
  char* ws = (char*)d_ws;
  float*    hbuf = (float*)(ws);                         // 67,108,864 B
  float*    fgm  = (float*)(ws + 67108864);              // 1,179,648 B
  float*    boxes= (float*)(ws + 68288512);              // 4,718,592 B
  float*    wT   = (float*)(ws + 73007104);              // 9,437,184 B
  float4*   selb = (float4*)(ws + 82444288);             // 262,144 B
  uint8_t*  selv = (uint8_t*)(ws + 82706432);            // 16,384 B
  uint64_t* mask = (uint64_t*)(ws + 82722816);           // 4,096,000 B  (end ~86.8MB)

  anchor_kernel<<<144, 256, 0, stream>>>(out);
  wt_kernel<<<9216, 256, 0, stream>>>(c1w, wT);
  conv3_v3<<<1024, 256, 0, stream>>>(x, wT, c1b, hbuf);
  heads_kernel<<<256, 256, 0, stream>>>(hbuf, sw, sb, lw, lb, out, fgm, boxes);
  select2_kernel<<<8, 1024, 0, stream>>>(fgm, boxes, selb, selv);
  nms_mask_kernel<<<2000, 256, 0, stream>>>(selb, mask);
  nms_scan_kernel<<<8, 64, 0, stream>>>(selv, mask, selb, out);
}

// Round 4
// 3249.366 us; speedup vs baseline: 1.3147x; 1.3147x over previous
//
#include <hip/hip_runtime.h>
#include <math.h>
#include <stdint.h>

#define NB 8
#define CIN 512
#define HW 4096
#define ANUM 9
#define NANC 36864
#define PRE 2000
#define POST 300

// d_out float offsets
#define OUT_LOCS   0
#define OUT_SCORES 1179648
#define OUT_ROIS   1769472
#define OUT_RIDX   1779072
#define OUT_ANC    1781472

typedef float v2f __attribute__((ext_vector_type(2)));

// ---------------- K0: anchors ----------------
__global__ void anchor_kernel(float* __restrict__ out) {
  int i = blockIdx.x * 256 + threadIdx.x;
  if (i >= NANC) return;
  int s = i / 9, a = i - s * 9;
  int y = s >> 6, x = s & 63;
  int ri = a / 3, si = a - ri * 3;
  double r = (ri == 0) ? 0.5 : (ri == 1 ? 1.0 : 2.0);
  double sc = (si == 0) ? 8.0 : (si == 1 ? 16.0 : 32.0);
  double hh = 16.0 * sc * sqrt(r);
  double ww = 16.0 * sc * sqrt(1.0 / r);
  float a0 = (float)(8.0 - hh * 0.5);
  float a1 = (float)(8.0 - ww * 0.5);
  float a2 = (float)(8.0 + hh * 0.5);
  float a3 = (float)(8.0 + ww * 0.5);
  float sy = (float)(y * 16), sx = (float)(x * 16);
  out[OUT_ANC + i * 4 + 0] = a0 + sy;
  out[OUT_ANC + i * 4 + 1] = a1 + sx;
  out[OUT_ANC + i * 4 + 2] = a2 + sy;
  out[OUT_ANC + i * 4 + 3] = a3 + sx;
}

// ---------------- K0b: weight transpose w[oc][ic][k] -> wT[ic][k][oc] ----------------
__global__ void wt_kernel(const float* __restrict__ w, float* __restrict__ wT) {
  int i = blockIdx.x * 256 + threadIdx.x;
  if (i >= CIN * 9 * CIN) return;
  int oc = i & 511;
  int rem = i >> 9;
  int k = rem % 9;
  int ic = rem / 9;
  wT[i] = w[((size_t)oc * CIN + ic) * 9 + k];
}

// ---------------- K1: conv3x3 + bias + relu ----------------
// v4 = v2 structure + packed fp32 FMA (v_pk_fma_f32) on the two q-columns.
// grid 1024: ocb(32) fastest, tile(4), n(8). 256 thr: rows{2ty,2ty+1}, cols{tx,tx+16}
__global__ __launch_bounds__(256, 4) void conv3_v4(
    const float* __restrict__ x, const float* __restrict__ wT,
    const float* __restrict__ bias, float* __restrict__ h) {
  __shared__ float xs[4][34][40];  // row stride 40 -> 2-way on reads (free)
  int blk = blockIdx.x;
  int ocb = blk & 31;
  int t = (blk >> 5) & 3;
  int n = blk >> 7;
  int ty0 = (t >> 1) * 32, tx0 = (t & 1) * 32;
  int tid = threadIdx.x;
  int ty = tid >> 4;
  int tx = tid & 15;

  v2f acc2[16][2];  // [o][p], .x = col tx, .y = col tx+16
#pragma unroll
  for (int o = 0; o < 16; o++)
#pragma unroll
    for (int p = 0; p < 2; p++) acc2[o][p] = (v2f){0.f, 0.f};

  const float* xn = x + (size_t)n * CIN * HW;
  const float* wb = wT + (ocb << 4);

#pragma unroll 1
  for (int ic0 = 0; ic0 < CIN; ic0 += 4) {
    for (int l = tid; l < 4 * 34 * 34; l += 256) {
      int ic = l / 1156; int rem = l - ic * 1156;
      int dy = rem / 34; int dx = rem - dy * 34;
      int gy = ty0 - 1 + dy, gx = tx0 - 1 + dx;
      float v = 0.f;
      if ((unsigned)gy < 64u && (unsigned)gx < 64u)
        v = xn[(size_t)(ic0 + ic) * HW + (gy << 6) + gx];
      xs[ic][dy][dx] = v;
    }
    __syncthreads();
#pragma unroll 1
    for (int ic = 0; ic < 4; ++ic) {
      v2f xv2[4][3];  // [r][c] = {xs[r][tx+c], xs[r][tx+16+c]}
#pragma unroll
      for (int r = 0; r < 4; ++r) {
#pragma unroll
        for (int c = 0; c < 3; ++c) {
          xv2[r][c].x = xs[ic][2 * ty + r][tx + c];
          xv2[r][c].y = xs[ic][2 * ty + r][tx + 16 + c];
        }
      }
      const float* wic = wb + (size_t)(ic0 + ic) * 9 * 512;
#pragma unroll
      for (int k = 0; k < 9; ++k) {
        int ky = k / 3, kx = k - ky * 3;
        const float4* wk = (const float4*)(wic + (k << 9));
        float4 w0 = wk[0], w1 = wk[1], w2 = wk[2], w3 = wk[3];
        float wv[16] = {w0.x, w0.y, w0.z, w0.w, w1.x, w1.y, w1.z, w1.w,
                        w2.x, w2.y, w2.z, w2.w, w3.x, w3.y, w3.z, w3.w};
#pragma unroll
        for (int o = 0; o < 16; ++o) {
          v2f wq = (v2f){wv[o], wv[o]};
          acc2[o][0] = __builtin_elementwise_fma(xv2[0 + ky][kx], wq, acc2[o][0]);
          acc2[o][1] = __builtin_elementwise_fma(xv2[1 + ky][kx], wq, acc2[o][1]);
        }
      }
    }
    __syncthreads();
  }
#pragma unroll
  for (int o = 0; o < 16; o++) {
    int oc = ocb * 16 + o;
    float bv = bias[oc];
#pragma unroll
    for (int p = 0; p < 2; p++) {
      int gy = ty0 + 2 * ty + p;
      float va = acc2[o][p].x + bv;
      float vb = acc2[o][p].y + bv;
      h[((size_t)n * CIN + oc) * HW + gy * 64 + tx0 + tx]      = va > 0.f ? va : 0.f;
      h[((size_t)n * CIN + oc) * HW + gy * 64 + tx0 + tx + 16] = vb > 0.f ? vb : 0.f;
    }
  }
}

// ---------------- K2: 1x1 heads + transpose + fg + box decode ----------------
__global__ __launch_bounds__(256) void heads_kernel(
    const float* __restrict__ h, const float* __restrict__ sw,
    const float* __restrict__ sb, const float* __restrict__ lw,
    const float* __restrict__ lb, float* __restrict__ out,
    float* __restrict__ fgm, float* __restrict__ boxes) {
  __shared__ float wlds[2][64][56];
  __shared__ float part[128][56];
  int tid = threadIdx.x;
  int sl = tid >> 7;
  int pl = tid & 127;
  int blk = blockIdx.x;
  int n = blk >> 5;
  int s0 = (blk & 31) * 128;

  float acc[54];
#pragma unroll
  for (int k = 0; k < 54; k++) acc[k] = 0.f;

  for (int cc = 0; cc < 256; cc += 64) {
    for (int l = tid; l < 2 * 64 * 54; l += 256) {
      int slc = l / (64 * 54); int rem = l - slc * 64 * 54;
      int cl = rem / 54; int k = rem - cl * 54;
      int c = slc * 256 + cc + cl;
      wlds[slc][cl][k] = (k < 18) ? sw[k * CIN + c] : lw[(k - 18) * CIN + c];
    }
    __syncthreads();
    int cbase = sl * 256 + cc;
    for (int cl = 0; cl < 64; ++cl) {
      float hv = h[((size_t)n * CIN + cbase + cl) * HW + s0 + pl];
#pragma unroll
      for (int k = 0; k < 54; ++k) acc[k] = fmaf(hv, wlds[sl][cl][k], acc[k]);
    }
    __syncthreads();
  }
  if (sl == 1) {
#pragma unroll
    for (int k = 0; k < 54; k++) part[pl][k] = acc[k];
  }
  __syncthreads();
  if (sl == 0) {
#pragma unroll
    for (int k = 0; k < 54; k++) acc[k] += part[pl][k];
    int s = s0 + pl;
    int y = s >> 6, xx = s & 63;
    float sc[18], lo[36];
#pragma unroll
    for (int k = 0; k < 18; k++) sc[k] = acc[k] + sb[k];
#pragma unroll
    for (int k = 0; k < 36; k++) lo[k] = acc[18 + k] + lb[k];
    size_t base = (size_t)n * NANC + (size_t)s * 9;
#pragma unroll
    for (int i = 0; i < 36; i++) out[OUT_LOCS + base * 4 + i] = lo[i];
#pragma unroll
    for (int i = 0; i < 18; i++) out[OUT_SCORES + base * 2 + i] = sc[i];
    float syf = (float)(y * 16), sxf = (float)(xx * 16);
#pragma unroll
    for (int a = 0; a < 9; a++) {
      float s0v = sc[a * 2], s1v = sc[a * 2 + 1];
      float m = fmaxf(s0v, s1v);
      float e0 = expf(s0v - m), e1 = expf(s1v - m);
      float fg = e1 / (e0 + e1);
      int ri = a / 3, si = a - ri * 3;
      double r = (ri == 0) ? 0.5 : (ri == 1 ? 1.0 : 2.0);
      double scd = (si == 0) ? 8.0 : (si == 1 ? 16.0 : 32.0);
      double hhd = 16.0 * scd * sqrt(r);
      double wwd = 16.0 * scd * sqrt(1.0 / r);
      float a0 = (float)(8.0 - hhd * 0.5) + syf;
      float a1 = (float)(8.0 - wwd * 0.5) + sxf;
      float a2 = (float)(8.0 + hhd * 0.5) + syf;
      float a3 = (float)(8.0 + wwd * 0.5) + sxf;
      float hA = a2 - a0, wA = a3 - a1;
      float cy = a0 + 0.5f * hA, cx = a1 + 0.5f * wA;
      float dy = lo[a * 4 + 0], dx = lo[a * 4 + 1];
      float dh = lo[a * 4 + 2], dw = lo[a * 4 + 3];
      float cy2 = dy * hA + cy, cx2 = dx * wA + cx;
      float h2 = expf(dh) * hA, w2 = expf(dw) * wA;
      float b0 = cy2 - 0.5f * h2, b1 = cx2 - 0.5f * w2;
      float b2 = cy2 + 0.5f * h2, b3 = cx2 + 0.5f * w2;
      b0 = fminf(fmaxf(b0, 0.f), 1024.f);
      b1 = fminf(fmaxf(b1, 0.f), 1024.f);
      b2 = fminf(fmaxf(b2, 0.f), 1024.f);
      b3 = fminf(fmaxf(b3, 0.f), 1024.f);
      float hs = b2 - b0, wss = b3 - b1;
      bool valid = (hs >= 16.f) && (wss >= 16.f);
      size_t bi = base + a;
      boxes[bi * 4 + 0] = b0; boxes[bi * 4 + 1] = b1;
      boxes[bi * 4 + 2] = b2; boxes[bi * 4 + 3] = b3;
      fgm[bi] = valid ? fg : -__builtin_inff();
    }
  }
}

// ---------------- K3: top-2000 (4-pass radix on 32-bit orderable score) ----------------
__device__ __forceinline__ uint32_t ord32(float v) {
  uint32_t s = __float_as_uint(v);
  return (s & 0x80000000u) ? ~s : (s | 0x80000000u);
}

__global__ __launch_bounds__(1024) void select2_kernel(
    const float* __restrict__ fgm, const float* __restrict__ boxes,
    float4* __restrict__ selb, uint8_t* __restrict__ selv) {
  int n = blockIdx.x;
  const float* f = fgm + (size_t)n * NANC;
  __shared__ uint32_t hist[256];
  __shared__ uint32_t segsum[16], segsufE[16];
  __shared__ uint64_t keys[2048];
  __shared__ uint32_t sh_digit, sh_T, scnt;
  int tid = threadIdx.x;
  uint32_t pref = 0;
  uint32_t T = PRE;
  for (int p = 0; p < 4; ++p) {
    int shift = 24 - 8 * p;
    if (tid < 256) hist[tid] = 0;
    __syncthreads();
    for (int i = tid; i < NANC; i += 1024) {
      uint32_t u = ord32(f[i]);
      bool match = (p == 0) || ((u >> (shift + 8)) == (pref >> (shift + 8)));
      if (match) atomicAdd(&hist[(u >> shift) & 255u], 1u);
    }
    __syncthreads();
    if (tid < 16) {
      uint32_t s = 0;
      for (int j = 0; j < 16; ++j) s += hist[tid * 16 + j];
      segsum[tid] = s;
    }
    __syncthreads();
    if (tid == 0) {
      uint32_t run = 0;
      for (int s = 15; s >= 0; --s) { segsufE[s] = run; run += segsum[s]; }
    }
    __syncthreads();
    if (tid < 256) {
      int d = tid, s = d >> 4;
      uint32_t loc = 0;
      for (int j = d; j < (s + 1) * 16; ++j) loc += hist[j];
      uint32_t suf = segsufE[s] + loc;
      uint32_t sufn = suf - hist[d];
      if (suf >= T && sufn < T) { sh_digit = (uint32_t)d; sh_T = T - sufn; }
    }
    __syncthreads();
    pref |= sh_digit << shift;
    T = sh_T;
    __syncthreads();
  }
  if (tid == 0) scnt = 0;
  __syncthreads();
  for (int i = tid; i < NANC; i += 1024) {
    uint32_t u = ord32(f[i]);
    if (u >= pref) {
      uint32_t pos = atomicAdd(&scnt, 1u);
      if (pos < 2048) keys[pos] = ((uint64_t)u << 32) | (uint32_t)(~(uint32_t)i);
    }
  }
  __syncthreads();
  uint32_t sc = scnt > 2048 ? 2048 : scnt;
  for (int i = sc + tid; i < 2048; i += 1024) keys[i] = 0;
  __syncthreads();
  for (int k = 2; k <= 2048; k <<= 1) {
    for (int j = k >> 1; j > 0; j >>= 1) {
      for (int e = tid; e < 2048; e += 1024) {
        int partner = e ^ j;
        if (partner > e) {
          bool up = ((e & k) == 0);
          uint64_t a = keys[e], b = keys[partner];
          if (up ? (a < b) : (a > b)) { keys[e] = b; keys[partner] = a; }
        }
      }
      __syncthreads();
    }
  }
  for (int t2 = tid; t2 < PRE; t2 += 1024) {
    uint64_t key = keys[t2];
    uint32_t idx = ~((uint32_t)(key & 0xFFFFFFFFu));
    const float4* bp = (const float4*)(boxes + ((size_t)n * NANC + idx) * 4);
    selb[(size_t)n * 2048 + t2] = *bp;
    selv[(size_t)n * 2048 + t2] = ((uint32_t)(key >> 32)) > 0x007FFFFFu ? 1 : 0;
  }
}

// ---------------- K4a: NMS suppression mask (grid-parallel) ----------------
// grid 2000 = 8 n * 250; block 256 = 8 i-rows x 32 j-words
__global__ __launch_bounds__(256) void nms_mask_kernel(
    const float4* __restrict__ selb, uint64_t* __restrict__ mask) {
  __shared__ float by0[PRE], bx0_[PRE], by1[PRE], bx1_[PRE], bar[PRE];
  int b = blockIdx.x;
  int n = b / 250;
  int i0 = (b % 250) * 8;
  int tid = threadIdx.x;
  for (int j = tid; j < PRE; j += 256) {
    float4 bb = selb[(size_t)n * 2048 + j];
    by0[j] = bb.x; bx0_[j] = bb.y; by1[j] = bb.z; bx1_[j] = bb.w;
    bar[j] = (bb.z - bb.x) * (bb.w - bb.y);
  }
  __syncthreads();
  int i = i0 + (tid >> 5);
  int jw = tid & 31;
  float iy0 = by0[i], ix0 = bx0_[i], iy1 = by1[i], ix1 = bx1_[i], ia = bar[i];
  uint64_t bits = 0;
  int jb = jw * 64;
  for (int tb = 0; tb < 64; ++tb) {
    int tbp = (tb + jw) & 63;  // swizzle to avoid 64-way LDS bank conflicts
    int j = jb + tbp;
    if (j < PRE && j > i) {
      float ty = fmaxf(iy0, by0[j]);
      float txx = fmaxf(ix0, bx0_[j]);
      float byv = fminf(iy1, by1[j]);
      float bxv = fminf(ix1, bx1_[j]);
      float ih = byv - ty; if (ih < 0.f) ih = 0.f;
      float iw = bxv - txx; if (iw < 0.f) iw = 0.f;
      float inter = ih * iw;
      float iou = inter / (ia + bar[j] - inter + 1e-9f);
      if (iou > 0.7f) bits |= (1ull << tbp);
    }
  }
  mask[((size_t)n * PRE + i) * 32 + jw] = bits;
}

// ---------------- K4b: serial bit-scan NMS + write rois (1 wave / image) ----------------
__global__ __launch_bounds__(64) void nms_scan_kernel(
    const uint8_t* __restrict__ selv, const uint64_t* __restrict__ mask,
    const float4* __restrict__ selb, float* __restrict__ out) {
  int n = blockIdx.x;
  int lane = threadIdx.x;
  const uint8_t* sv = selv + (size_t)n * 2048;
  uint64_t kw = 0;
  for (int wblk = 0; wblk < 32; ++wblk) {
    int j = wblk * 64 + lane;
    bool pred = (j < PRE) && (sv[j] != 0);
    uint64_t m = __ballot(pred);
    if (lane == wblk) kw = m;
  }
  const uint64_t* mrow = mask + (size_t)n * PRE * 32;
  for (int i0 = 0; i0 < PRE; i0 += 16) {
    uint64_t rr[16];
#pragma unroll
    for (int tt = 0; tt < 16; ++tt)
      rr[tt] = (lane < 32) ? mrow[(size_t)(i0 + tt) * 32 + lane] : 0;
#pragma unroll
    for (int tt = 0; tt < 16; ++tt) {
      int i = i0 + tt;
      uint64_t w = __shfl(kw, i >> 6);
      if ((w >> (i & 63)) & 1ull) kw &= ~rr[tt];
    }
  }
  uint64_t kwv = (lane < 32) ? kw : 0ull;
  int pc = __popcll(kwv);
  int pre = pc;
  for (int d = 1; d < 64; d <<= 1) {
    int v = __shfl_up(pre, d);
    if (lane >= d) pre += v;
  }
  int total = __shfl(pre, 63);
  int rank = pre - pc;
  uint64_t bits = kwv;
  while (bits) {
    int bpos = __ffsll((unsigned long long)bits) - 1;
    bits &= bits - 1;
    if (rank < POST) {
      int j = lane * 64 + bpos;
      float4 bx = selb[(size_t)n * 2048 + j];
      size_t o = (size_t)OUT_ROIS + ((size_t)n * POST + rank) * 4;
      out[o + 0] = bx.x; out[o + 1] = bx.y; out[o + 2] = bx.z; out[o + 3] = bx.w;
    }
    rank++;
  }
  int cnt = total > POST ? POST : total;
  for (int r2 = cnt + lane; r2 < POST; r2 += 64) {
    size_t o = (size_t)OUT_ROIS + ((size_t)n * POST + r2) * 4;
    out[o + 0] = 0.f; out[o + 1] = 0.f; out[o + 2] = 0.f; out[o + 3] = 0.f;
  }
  for (int r2 = lane; r2 < POST; r2 += 64)
    out[OUT_RIDX + n * POST + r2] = (float)n;
}

extern "C" void kernel_launch(void* const* d_in, const int* in_sizes, int n_in,
                              void* d_out, int out_size, void* d_ws, size_t ws_size,
                              hipStream_t stream) {
  const float* x   = (const float*)d_in[0];
  const float* c1w = (const float*)d_in[1];
  const float* c1b = (const float*)d_in[2];
  const float* sw  = (const float*)d_in[3];
  const float* sb  = (const float*)d_in[4];
  const float* lw  = (const float*)d_in[5];
  const float* lb  = (const float*)d_in[6];
  float* out = (float*)d_out;
  char* ws = (char*)d_ws;
  float*    hbuf = (float*)(ws);                         // 67,108,864 B
  float*    fgm  = (float*)(ws + 67108864);              // 1,179,648 B
  float*    boxes= (float*)(ws + 68288512);              // 4,718,592 B
  float*    wT   = (float*)(ws + 73007104);              // 9,437,184 B
  float4*   selb = (float4*)(ws + 82444288);             // 262,144 B
  uint8_t*  selv = (uint8_t*)(ws + 82706432);            // 16,384 B
  uint64_t* mask = (uint64_t*)(ws + 82722816);           // 4,096,000 B  (end ~86.8MB)

  anchor_kernel<<<144, 256, 0, stream>>>(out);
  wt_kernel<<<9216, 256, 0, stream>>>(c1w, wT);
  conv3_v4<<<1024, 256, 0, stream>>>(x, wT, c1b, hbuf);
  heads_kernel<<<256, 256, 0, stream>>>(hbuf, sw, sb, lw, lb, out, fgm, boxes);
  select2_kernel<<<8, 1024, 0, stream>>>(fgm, boxes, selb, selv);
  nms_mask_kernel<<<2000, 256, 0, stream>>>(selb, mask);
  nms_scan_kernel<<<8, 64, 0, stream>>>(selv, mask, selb, out);
}

// Round 6
// 2221.023 us; speedup vs baseline: 1.9234x; 1.4630x over previous
//
#include <hip/hip_runtime.h>
#include <math.h>
#include <stdint.h>

#define NB 8
#define CIN 512
#define HW 4096
#define ANUM 9
#define NANC 36864
#define PRE 2000
#define POST 300

// d_out float offsets
#define OUT_LOCS   0
#define OUT_SCORES 1179648
#define OUT_ROIS   1769472
#define OUT_RIDX   1779072
#define OUT_ANC    1781472

typedef _Float16 half8 __attribute__((ext_vector_type(8)));
typedef _Float16 half2_ __attribute__((ext_vector_type(2)));
typedef float f32x4 __attribute__((ext_vector_type(4)));

#define WSCALE 256.0f
#define LSCALE 4096.0f
#define INV_WS (1.0f / 256.0f)
#define INV_LS (1.0f / 4096.0f)

// ---------------- K0: anchors ----------------
__global__ void anchor_kernel(float* __restrict__ out) {
  int i = blockIdx.x * 256 + threadIdx.x;
  if (i >= NANC) return;
  int s = i / 9, a = i - s * 9;
  int y = s >> 6, x = s & 63;
  int ri = a / 3, si = a - ri * 3;
  double r = (ri == 0) ? 0.5 : (ri == 1 ? 1.0 : 2.0);
  double sc = (si == 0) ? 8.0 : (si == 1 ? 16.0 : 32.0);
  double hh = 16.0 * sc * sqrt(r);
  double ww = 16.0 * sc * sqrt(1.0 / r);
  float a0 = (float)(8.0 - hh * 0.5);
  float a1 = (float)(8.0 - ww * 0.5);
  float a2 = (float)(8.0 + hh * 0.5);
  float a3 = (float)(8.0 + ww * 0.5);
  float sy = (float)(y * 16), sx = (float)(x * 16);
  out[OUT_ANC + i * 4 + 0] = a0 + sy;
  out[OUT_ANC + i * 4 + 1] = a1 + sx;
  out[OUT_ANC + i * 4 + 2] = a2 + sy;
  out[OUT_ANC + i * 4 + 3] = a3 + sx;
}

// ---------------- K0b: weight limb-split into B-fragment layout ----------------
// Weights pre-scaled x256 so hi limbs are f16-normal; lo limbs scaled x4096.
// frag id = (((tap*16 + icb)*32 + ob16)*2 + limb); elem = fid*512 + lane*8 + j
// B[k = (lane>>4)*8 + j][n = lane&15] ; ic = icb*32 + k ; oc = ob16*16 + n
__global__ void wprep_kernel(const float* __restrict__ w, _Float16* __restrict__ Bf) {
  int i = blockIdx.x * 256 + threadIdx.x;  // < 4718592
  int j = i & 7;
  int l = (i >> 3) & 63;
  int limb = (i >> 9) & 1;
  int ob = (i >> 10) & 31;
  int icb = (i >> 15) & 15;
  int tap = i >> 19;
  int ic = icb * 32 + ((l >> 4) << 3) + j;
  int oc = (ob << 4) + (l & 15);
  float v = w[((size_t)oc * CIN + ic) * 9 + tap] * WSCALE;
  _Float16 hi = (_Float16)v;
  Bf[i] = limb ? (_Float16)((v - (float)hi) * LSCALE) : hi;
}

// ---------------- K1: conv3x3 + bias + relu via MFMA (scaled f16 limbs, 3 products) ----------------
// grid 1024: ntblk = blk&7 (oc tile of 64, XCD-affine), mb = blk>>3: img(8) x 16 spatial tiles 16x16.
// block 256 = 4 waves; wave w: rows 4w..4w+3 x 64 oc (4 n-tiles).
// acc0 = xh*wh ; accC = xh*wl + xl*wh (carry 1/4096) ; h = (acc0 + accC/4096)/256 + b
__global__ __launch_bounds__(256) void conv3_mfma(
    const float* __restrict__ x, const _Float16* __restrict__ Bf,
    const float* __restrict__ bias, float* __restrict__ h) {
  __shared__ _Float16 xhi[10368];  // [pos=18*18][ic=32]
  __shared__ _Float16 xlo[10368];
  int blk = blockIdx.x;
  int ntblk = blk & 7;
  int mb = blk >> 3;
  int img = mb >> 4;
  int t16 = mb & 15;
  int ty0 = (t16 >> 2) << 4, tx0 = (t16 & 3) << 4;
  int tid = threadIdx.x;
  int wv = tid >> 6, lane = tid & 63;
  int col = lane & 15, quad = lane >> 4;

  f32x4 acc0[4][4], accC[4][4];
#pragma unroll
  for (int g = 0; g < 4; ++g)
#pragma unroll
    for (int nt = 0; nt < 4; ++nt) {
      acc0[g][nt] = (f32x4){0.f, 0.f, 0.f, 0.f};
      accC[g][nt] = (f32x4){0.f, 0.f, 0.f, 0.f};
    }

  const float* xn = x + (size_t)img * CIN * HW;
  const half8* B8 = (const half8*)Bf;

  int abase[4];
#pragma unroll
  for (int g = 0; g < 4; ++g)
    abase[g] = ((4 * wv + g) * 18 + col) * 32 + quad * 8;

#pragma unroll 1
  for (int icb = 0; icb < 16; ++icb) {
    __syncthreads();
    const float* xb = xn + (size_t)icb * 32 * HW;
#pragma unroll 1
    for (int i = 0; i < 21; ++i) {
      int l = tid + (i << 8);
      if (l < 5184) {
        int icp = l / 324;
        int pos = l - icp * 324;
        int py = pos / 18, px = pos - py * 18;
        int gy = ty0 - 1 + py, gx = tx0 - 1 + px;
        float v0 = 0.f, v1 = 0.f;
        if ((unsigned)gy < 64u && (unsigned)gx < 64u) {
          int go = (icp * 2) * HW + (gy << 6) + gx;
          v0 = xb[go];
          v1 = xb[go + HW];
        }
        _Float16 h0 = (_Float16)v0, h1 = (_Float16)v1;
        _Float16 l0 = (_Float16)((v0 - (float)h0) * LSCALE);
        _Float16 l1 = (_Float16)((v1 - (float)h1) * LSCALE);
        int a = (pos << 5) + (icp << 1);
        *(half2_*)(xhi + a) = (half2_){h0, h1};
        *(half2_*)(xlo + a) = (half2_){l0, l1};
      }
    }
    __syncthreads();
#pragma unroll
    for (int ky = 0; ky < 3; ++ky) {
#pragma unroll
      for (int kx = 0; kx < 3; ++kx) {
        int tap = ky * 3 + kx;
        int toff = (ky * 18 + kx) << 5;
        half8 Ah[4], Al[4];
#pragma unroll
        for (int g = 0; g < 4; ++g) {
          Ah[g] = *(const half8*)(xhi + abase[g] + toff);
          Al[g] = *(const half8*)(xlo + abase[g] + toff);
        }
#pragma unroll
        for (int nt = 0; nt < 4; ++nt) {
          int fid = (((tap * 16 + icb) * 32 + (ntblk << 2) + nt) << 1);
          half8 Bh = B8[(size_t)fid * 64 + lane];
          half8 Bl = B8[(size_t)(fid + 1) * 64 + lane];
#pragma unroll
          for (int g = 0; g < 4; ++g) {
            acc0[g][nt] = __builtin_amdgcn_mfma_f32_16x16x32_f16(Ah[g], Bh, acc0[g][nt], 0, 0, 0);
            accC[g][nt] = __builtin_amdgcn_mfma_f32_16x16x32_f16(Ah[g], Bl, accC[g][nt], 0, 0, 0);
            accC[g][nt] = __builtin_amdgcn_mfma_f32_16x16x32_f16(Al[g], Bh, accC[g][nt], 0, 0, 0);
          }
        }
      }
    }
  }
  // epilogue: C/D layout col=lane&15 (oc), row=quad*4+reg (spatial col) -> float4 store
#pragma unroll
  for (int g = 0; g < 4; ++g) {
#pragma unroll
    for (int nt = 0; nt < 4; ++nt) {
      int oc = (ntblk << 6) + (nt << 4) + col;
      float bv = bias[oc];
      int gy = ty0 + 4 * wv + g;
      int gx0 = tx0 + (quad << 2);
      f32x4 a0 = acc0[g][nt];
      f32x4 ac = accC[g][nt];
      float4 o;
      o.x = fmaf(ac.x, INV_LS, a0.x) * INV_WS + bv; o.x = o.x > 0.f ? o.x : 0.f;
      o.y = fmaf(ac.y, INV_LS, a0.y) * INV_WS + bv; o.y = o.y > 0.f ? o.y : 0.f;
      o.z = fmaf(ac.z, INV_LS, a0.z) * INV_WS + bv; o.z = o.z > 0.f ? o.z : 0.f;
      o.w = fmaf(ac.w, INV_LS, a0.w) * INV_WS + bv; o.w = o.w > 0.f ? o.w : 0.f;
      *(float4*)(h + ((size_t)img * CIN + oc) * HW + (gy << 6) + gx0) = o;
    }
  }
}

// ---------------- K2: 1x1 heads + transpose + fg + box decode ----------------
__global__ __launch_bounds__(256) void heads_kernel(
    const float* __restrict__ h, const float* __restrict__ sw,
    const float* __restrict__ sb, const float* __restrict__ lw,
    const float* __restrict__ lb, float* __restrict__ out,
    float* __restrict__ fgm, float* __restrict__ boxes) {
  __shared__ float wlds[2][64][56];
  __shared__ float part[128][56];
  int tid = threadIdx.x;
  int sl = tid >> 7;
  int pl = tid & 127;
  int blk = blockIdx.x;
  int n = blk >> 5;
  int s0 = (blk & 31) * 128;

  float acc[54];
#pragma unroll
  for (int k = 0; k < 54; k++) acc[k] = 0.f;

  for (int cc = 0; cc < 256; cc += 64) {
    for (int l = tid; l < 2 * 64 * 54; l += 256) {
      int slc = l / (64 * 54); int rem = l - slc * 64 * 54;
      int cl = rem / 54; int k = rem - cl * 54;
      int c = slc * 256 + cc + cl;
      wlds[slc][cl][k] = (k < 18) ? sw[k * CIN + c] : lw[(k - 18) * CIN + c];
    }
    __syncthreads();
    int cbase = sl * 256 + cc;
    for (int cl = 0; cl < 64; ++cl) {
      float hv = h[((size_t)n * CIN + cbase + cl) * HW + s0 + pl];
#pragma unroll
      for (int k = 0; k < 54; ++k) acc[k] = fmaf(hv, wlds[sl][cl][k], acc[k]);
    }
    __syncthreads();
  }
  if (sl == 1) {
#pragma unroll
    for (int k = 0; k < 54; k++) part[pl][k] = acc[k];
  }
  __syncthreads();
  if (sl == 0) {
#pragma unroll
    for (int k = 0; k < 54; k++) acc[k] += part[pl][k];
    int s = s0 + pl;
    int y = s >> 6, xx = s & 63;
    float sc[18], lo[36];
#pragma unroll
    for (int k = 0; k < 18; k++) sc[k] = acc[k] + sb[k];
#pragma unroll
    for (int k = 0; k < 36; k++) lo[k] = acc[18 + k] + lb[k];
    size_t base = (size_t)n * NANC + (size_t)s * 9;
#pragma unroll
    for (int i = 0; i < 36; i++) out[OUT_LOCS + base * 4 + i] = lo[i];
#pragma unroll
    for (int i = 0; i < 18; i++) out[OUT_SCORES + base * 2 + i] = sc[i];
    float syf = (float)(y * 16), sxf = (float)(xx * 16);
#pragma unroll
    for (int a = 0; a < 9; a++) {
      float s0v = sc[a * 2], s1v = sc[a * 2 + 1];
      float m = fmaxf(s0v, s1v);
      float e0 = expf(s0v - m), e1 = expf(s1v - m);
      float fg = e1 / (e0 + e1);
      int ri = a / 3, si = a - ri * 3;
      double r = (ri == 0) ? 0.5 : (ri == 1 ? 1.0 : 2.0);
      double scd = (si == 0) ? 8.0 : (si == 1 ? 16.0 : 32.0);
      double hhd = 16.0 * scd * sqrt(r);
      double wwd = 16.0 * scd * sqrt(1.0 / r);
      float a0 = (float)(8.0 - hhd * 0.5) + syf;
      float a1 = (float)(8.0 - wwd * 0.5) + sxf;
      float a2 = (float)(8.0 + hhd * 0.5) + syf;
      float a3 = (float)(8.0 + wwd * 0.5) + sxf;
      float hA = a2 - a0, wA = a3 - a1;
      float cy = a0 + 0.5f * hA, cx = a1 + 0.5f * wA;
      float dy = lo[a * 4 + 0], dx = lo[a * 4 + 1];
      float dh = lo[a * 4 + 2], dw = lo[a * 4 + 3];
      float cy2 = dy * hA + cy, cx2 = dx * wA + cx;
      float h2 = expf(dh) * hA, w2 = expf(dw) * wA;
      float b0 = cy2 - 0.5f * h2, b1 = cx2 - 0.5f * w2;
      float b2 = cy2 + 0.5f * h2, b3 = cx2 + 0.5f * w2;
      b0 = fminf(fmaxf(b0, 0.f), 1024.f);
      b1 = fminf(fmaxf(b1, 0.f), 1024.f);
      b2 = fminf(fmaxf(b2, 0.f), 1024.f);
      b3 = fminf(fmaxf(b3, 0.f), 1024.f);
      float hs = b2 - b0, wss = b3 - b1;
      bool valid = (hs >= 16.f) && (wss >= 16.f);
      size_t bi = base + a;
      boxes[bi * 4 + 0] = b0; boxes[bi * 4 + 1] = b1;
      boxes[bi * 4 + 2] = b2; boxes[bi * 4 + 3] = b3;
      fgm[bi] = valid ? fg : -__builtin_inff();
    }
  }
}

// ---------------- K3: top-2000 (4-pass radix on 32-bit orderable score) ----------------
__device__ __forceinline__ uint32_t ord32(float v) {
  uint32_t s = __float_as_uint(v);
  return (s & 0x80000000u) ? ~s : (s | 0x80000000u);
}

__global__ __launch_bounds__(1024) void select2_kernel(
    const float* __restrict__ fgm, const float* __restrict__ boxes,
    float4* __restrict__ selb, uint8_t* __restrict__ selv) {
  int n = blockIdx.x;
  const float* f = fgm + (size_t)n * NANC;
  __shared__ uint32_t hist[256];
  __shared__ uint32_t segsum[16], segsufE[16];
  __shared__ uint64_t keys[2048];
  __shared__ uint32_t sh_digit, sh_T, scnt;
  int tid = threadIdx.x;
  uint32_t pref = 0;
  uint32_t T = PRE;
  for (int p = 0; p < 4; ++p) {
    int shift = 24 - 8 * p;
    if (tid < 256) hist[tid] = 0;
    __syncthreads();
    for (int i = tid; i < NANC; i += 1024) {
      uint32_t u = ord32(f[i]);
      bool match = (p == 0) || ((u >> (shift + 8)) == (pref >> (shift + 8)));
      if (match) atomicAdd(&hist[(u >> shift) & 255u], 1u);
    }
    __syncthreads();
    if (tid < 16) {
      uint32_t s = 0;
      for (int j = 0; j < 16; ++j) s += hist[tid * 16 + j];
      segsum[tid] = s;
    }
    __syncthreads();
    if (tid == 0) {
      uint32_t run = 0;
      for (int s = 15; s >= 0; --s) { segsufE[s] = run; run += segsum[s]; }
    }
    __syncthreads();
    if (tid < 256) {
      int d = tid, s = d >> 4;
      uint32_t loc = 0;
      for (int j = d; j < (s + 1) * 16; ++j) loc += hist[j];
      uint32_t suf = segsufE[s] + loc;
      uint32_t sufn = suf - hist[d];
      if (suf >= T && sufn < T) { sh_digit = (uint32_t)d; sh_T = T - sufn; }
    }
    __syncthreads();
    pref |= sh_digit << shift;
    T = sh_T;
    __syncthreads();
  }
  if (tid == 0) scnt = 0;
  __syncthreads();
  for (int i = tid; i < NANC; i += 1024) {
    uint32_t u = ord32(f[i]);
    if (u >= pref) {
      uint32_t pos = atomicAdd(&scnt, 1u);
      if (pos < 2048) keys[pos] = ((uint64_t)u << 32) | (uint32_t)(~(uint32_t)i);
    }
  }
  __syncthreads();
  uint32_t sc = scnt > 2048 ? 2048 : scnt;
  for (int i = sc + tid; i < 2048; i += 1024) keys[i] = 0;
  __syncthreads();
  for (int k = 2; k <= 2048; k <<= 1) {
    for (int j = k >> 1; j > 0; j >>= 1) {
      for (int e = tid; e < 2048; e += 1024) {
        int partner = e ^ j;
        if (partner > e) {
          bool up = ((e & k) == 0);
          uint64_t a = keys[e], b = keys[partner];
          if (up ? (a < b) : (a > b)) { keys[e] = b; keys[partner] = a; }
        }
      }
      __syncthreads();
    }
  }
  for (int t2 = tid; t2 < PRE; t2 += 1024) {
    uint64_t key = keys[t2];
    uint32_t idx = ~((uint32_t)(key & 0xFFFFFFFFu));
    const float4* bp = (const float4*)(boxes + ((size_t)n * NANC + idx) * 4);
    selb[(size_t)n * 2048 + t2] = *bp;
    selv[(size_t)n * 2048 + t2] = ((uint32_t)(key >> 32)) > 0x007FFFFFu ? 1 : 0;
  }
}

// ---------------- K4a: NMS suppression mask (grid-parallel) ----------------
__global__ __launch_bounds__(256) void nms_mask_kernel(
    const float4* __restrict__ selb, uint64_t* __restrict__ mask) {
  __shared__ float by0[PRE], bx0_[PRE], by1[PRE], bx1_[PRE], bar[PRE];
  int b = blockIdx.x;
  int n = b / 250;
  int i0 = (b % 250) * 8;
  int tid = threadIdx.x;
  for (int j = tid; j < PRE; j += 256) {
    float4 bb = selb[(size_t)n * 2048 + j];
    by0[j] = bb.x; bx0_[j] = bb.y; by1[j] = bb.z; bx1_[j] = bb.w;
    bar[j] = (bb.z - bb.x) * (bb.w - bb.y);
  }
  __syncthreads();
  int i = i0 + (tid >> 5);
  int jw = tid & 31;
  float iy0 = by0[i], ix0 = bx0_[i], iy1 = by1[i], ix1 = bx1_[i], ia = bar[i];
  uint64_t bits = 0;
  int jb = jw * 64;
  for (int tb = 0; tb < 64; ++tb) {
    int tbp = (tb + jw) & 63;
    int j = jb + tbp;
    if (j < PRE && j > i) {
      float ty = fmaxf(iy0, by0[j]);
      float txx = fmaxf(ix0, bx0_[j]);
      float byv = fminf(iy1, by1[j]);
      float bxv = fminf(ix1, bx1_[j]);
      float ih = byv - ty; if (ih < 0.f) ih = 0.f;
      float iw = bxv - txx; if (iw < 0.f) iw = 0.f;
      float inter = ih * iw;
      float iou = inter / (ia + bar[j] - inter + 1e-9f);
      if (iou > 0.7f) bits |= (1ull << tbp);
    }
  }
  mask[((size_t)n * PRE + i) * 32 + jw] = bits;
}

// ---------------- K4b: serial bit-scan NMS + write rois (1 wave / image) ----------------
__global__ __launch_bounds__(64) void nms_scan_kernel(
    const uint8_t* __restrict__ selv, const uint64_t* __restrict__ mask,
    const float4* __restrict__ selb, float* __restrict__ out) {
  int n = blockIdx.x;
  int lane = threadIdx.x;
  const uint8_t* sv = selv + (size_t)n * 2048;
  uint64_t kw = 0;
  for (int wblk = 0; wblk < 32; ++wblk) {
    int j = wblk * 64 + lane;
    bool pred = (j < PRE) && (sv[j] != 0);
    uint64_t m = __ballot(pred);
    if (lane == wblk) kw = m;
  }
  const uint64_t* mrow = mask + (size_t)n * PRE * 32;
  for (int i0 = 0; i0 < PRE; i0 += 16) {
    uint64_t rr[16];
#pragma unroll
    for (int tt = 0; tt < 16; ++tt)
      rr[tt] = (lane < 32) ? mrow[(size_t)(i0 + tt) * 32 + lane] : 0;
#pragma unroll
    for (int tt = 0; tt < 16; ++tt) {
      int i = i0 + tt;
      uint64_t w = __shfl(kw, i >> 6);
      if ((w >> (i & 63)) & 1ull) kw &= ~rr[tt];
    }
  }
  uint64_t kwv = (lane < 32) ? kw : 0ull;
  int pc = __popcll(kwv);
  int pre = pc;
  for (int d = 1; d < 64; d <<= 1) {
    int v = __shfl_up(pre, d);
    if (lane >= d) pre += v;
  }
  int total = __shfl(pre, 63);
  int rank = pre - pc;
  uint64_t bits = kwv;
  while (bits) {
    int bpos = __ffsll((unsigned long long)bits) - 1;
    bits &= bits - 1;
    if (rank < POST) {
      int j = lane * 64 + bpos;
      float4 bx = selb[(size_t)n * 2048 + j];
      size_t o = (size_t)OUT_ROIS + ((size_t)n * POST + rank) * 4;
      out[o + 0] = bx.x; out[o + 1] = bx.y; out[o + 2] = bx.z; out[o + 3] = bx.w;
    }
    rank++;
  }
  int cnt = total > POST ? POST : total;
  for (int r2 = cnt + lane; r2 < POST; r2 += 64) {
    size_t o = (size_t)OUT_ROIS + ((size_t)n * POST + r2) * 4;
    out[o + 0] = 0.f; out[o + 1] = 0.f; out[o + 2] = 0.f; out[o + 3] = 0.f;
  }
  for (int r2 = lane; r2 < POST; r2 += 64)
    out[OUT_RIDX + n * POST + r2] = (float)n;
}

extern "C" void kernel_launch(void* const* d_in, const int* in_sizes, int n_in,
                              void* d_out, int out_size, void* d_ws, size_t ws_size,
                              hipStream_t stream) {
  const float* x   = (const float*)d_in[0];
  const float* c1w = (const float*)d_in[1];
  const float* c1b = (const float*)d_in[2];
  const float* sw  = (const float*)d_in[3];
  const float* sb  = (const float*)d_in[4];
  const float* lw  = (const float*)d_in[5];
  const float* lb  = (const float*)d_in[6];
  float* out = (float*)d_out;
  char* ws = (char*)d_ws;
  float*     hbuf = (float*)(ws);                        // 67,108,864 B
  float*     fgm  = (float*)(ws + 67108864);             // 1,179,648 B
  float*     boxes= (float*)(ws + 68288512);             // 4,718,592 B
  _Float16*  Bf   = (_Float16*)(ws + 73007104);          // 9,437,184 B (4,718,592 f16)
  float4*    selb = (float4*)(ws + 82444288);            // 262,144 B
  uint8_t*   selv = (uint8_t*)(ws + 82706432);           // 16,384 B
  uint64_t*  mask = (uint64_t*)(ws + 82722816);          // 4,096,000 B

  anchor_kernel<<<144, 256, 0, stream>>>(out);
  wprep_kernel<<<18432, 256, 0, stream>>>(c1w, Bf);
  conv3_mfma<<<1024, 256, 0, stream>>>(x, Bf, c1b, hbuf);
  heads_kernel<<<256, 256, 0, stream>>>(hbuf, sw, sb, lw, lb, out, fgm, boxes);
  select2_kernel<<<8, 1024, 0, stream>>>(fgm, boxes, selb, selv);
  nms_mask_kernel<<<2000, 256, 0, stream>>>(selb, mask);
  nms_scan_kernel<<<8, 64, 0, stream>>>(selv, mask, selb, out);
}

// Round 7
// 1592.772 us; speedup vs baseline: 2.6821x; 1.3944x over previous
//
#include <hip/hip_runtime.h>
#include <math.h>
#include <stdint.h>

#define NB 8
#define CIN 512
#define HW 4096
#define ANUM 9
#define NANC 36864
#define PRE 2000
#define POST 300

// d_out float offsets
#define OUT_LOCS   0
#define OUT_SCORES 1179648
#define OUT_ROIS   1769472
#define OUT_RIDX   1779072
#define OUT_ANC    1781472

typedef _Float16 half8 __attribute__((ext_vector_type(8)));
typedef _Float16 half4_ __attribute__((ext_vector_type(4)));
typedef float f32x4 __attribute__((ext_vector_type(4)));

#define WSCALE 256.0f
#define LSCALE 4096.0f
#define INV_WS (1.0f / 256.0f)
#define INV_LS (1.0f / 4096.0f)
#define XS_STRIDE 40  // halfs per halo position (32 data + 8 pad) -> conflict-free b128/b64

// ---------------- K0: anchors ----------------
__global__ void anchor_kernel(float* __restrict__ out) {
  int i = blockIdx.x * 256 + threadIdx.x;
  if (i >= NANC) return;
  int s = i / 9, a = i - s * 9;
  int y = s >> 6, x = s & 63;
  int ri = a / 3, si = a - ri * 3;
  double r = (ri == 0) ? 0.5 : (ri == 1 ? 1.0 : 2.0);
  double sc = (si == 0) ? 8.0 : (si == 1 ? 16.0 : 32.0);
  double hh = 16.0 * sc * sqrt(r);
  double ww = 16.0 * sc * sqrt(1.0 / r);
  float a0 = (float)(8.0 - hh * 0.5);
  float a1 = (float)(8.0 - ww * 0.5);
  float a2 = (float)(8.0 + hh * 0.5);
  float a3 = (float)(8.0 + ww * 0.5);
  float sy = (float)(y * 16), sx = (float)(x * 16);
  out[OUT_ANC + i * 4 + 0] = a0 + sy;
  out[OUT_ANC + i * 4 + 1] = a1 + sx;
  out[OUT_ANC + i * 4 + 2] = a2 + sy;
  out[OUT_ANC + i * 4 + 3] = a3 + sx;
}

// ---------------- K0b: weight limb-split into B-fragment layout (unchanged) ----------------
// frag id = (((tap*16 + icb)*32 + ob16)*2 + limb); elem = fid*512 + lane*8 + j
// B[k = (lane>>4)*8 + j][n = lane&15] ; ic = icb*32 + k ; oc = ob16*16 + n
__global__ void wprep_kernel(const float* __restrict__ w, _Float16* __restrict__ Bf) {
  int i = blockIdx.x * 256 + threadIdx.x;  // < 4718592
  int j = i & 7;
  int l = (i >> 3) & 63;
  int limb = (i >> 9) & 1;
  int ob = (i >> 10) & 31;
  int icb = (i >> 15) & 15;
  int tap = i >> 19;
  int ic = icb * 32 + ((l >> 4) << 3) + j;
  int oc = (ob << 4) + (l & 15);
  float v = w[((size_t)oc * CIN + ic) * 9 + tap] * WSCALE;
  _Float16 hi = (_Float16)v;
  Bf[i] = limb ? (_Float16)((v - (float)hi) * LSCALE) : hi;
}

// ---------------- K1: conv3x3 + bias + relu via MFMA (scaled f16 limbs) ----------------
// v2: padded LDS (conflict-free), b64 staging writes, 4m x 2n per wave (64 acc regs ->
// ~3 waves/SIMD). grid 2048: ntblk = blk&15 (oc tile 32, XCD-affine), img(8) x 16 tiles.
__global__ __launch_bounds__(256) void conv3_mfma(
    const float* __restrict__ x, const _Float16* __restrict__ Bf,
    const float* __restrict__ bias, float* __restrict__ h) {
  __shared__ _Float16 xhi[324 * XS_STRIDE];  // 25,920 B
  __shared__ _Float16 xlo[324 * XS_STRIDE];  // 25,920 B
  int blk = blockIdx.x;
  int ntblk = blk & 15;
  int mb = blk >> 4;
  int img = mb >> 4;
  int t16 = mb & 15;
  int ty0 = (t16 >> 2) << 4, tx0 = (t16 & 3) << 4;
  int tid = threadIdx.x;
  int wv = tid >> 6, lane = tid & 63;
  int col = lane & 15, quad = lane >> 4;

  f32x4 acc0[4][2], accC[4][2];
#pragma unroll
  for (int g = 0; g < 4; ++g)
#pragma unroll
    for (int nt = 0; nt < 2; ++nt) {
      acc0[g][nt] = (f32x4){0.f, 0.f, 0.f, 0.f};
      accC[g][nt] = (f32x4){0.f, 0.f, 0.f, 0.f};
    }

  const float* xn = x + (size_t)img * CIN * HW;
  const half8* B8 = (const half8*)Bf;

  int abase[4];
#pragma unroll
  for (int g = 0; g < 4; ++g)
    abase[g] = ((4 * wv + g) * 18 + col) * XS_STRIDE + quad * 8;

#pragma unroll 1
  for (int icb = 0; icb < 16; ++icb) {
    __syncthreads();
    const float* xb = xn + (size_t)icb * 32 * HW;
    // stage 18x18 halo x 32 ic: slot = icg(8) * 324 + pos; 4 ic per slot, b64 LDS writes
#pragma unroll 1
    for (int i = 0; i < 11; ++i) {
      int l = tid + (i << 8);
      if (l < 2592) {
        int icg = l / 324;
        int pos = l - icg * 324;
        int py = pos / 18, px = pos - py * 18;
        int gy = ty0 - 1 + py, gx = tx0 - 1 + px;
        float v0 = 0.f, v1 = 0.f, v2 = 0.f, v3 = 0.f;
        if ((unsigned)gy < 64u && (unsigned)gx < 64u) {
          const float* p = xb + (size_t)(icg * 4) * HW + (gy << 6) + gx;
          v0 = p[0]; v1 = p[HW]; v2 = p[2 * HW]; v3 = p[3 * HW];
        }
        _Float16 h0 = (_Float16)v0, h1 = (_Float16)v1;
        _Float16 h2 = (_Float16)v2, h3 = (_Float16)v3;
        _Float16 e0 = (_Float16)((v0 - (float)h0) * LSCALE);
        _Float16 e1 = (_Float16)((v1 - (float)h1) * LSCALE);
        _Float16 e2 = (_Float16)((v2 - (float)h2) * LSCALE);
        _Float16 e3 = (_Float16)((v3 - (float)h3) * LSCALE);
        int a = pos * XS_STRIDE + icg * 4;
        *(half4_*)(xhi + a) = (half4_){h0, h1, h2, h3};
        *(half4_*)(xlo + a) = (half4_){e0, e1, e2, e3};
      }
    }
    __syncthreads();
#pragma unroll
    for (int ky = 0; ky < 3; ++ky) {
#pragma unroll
      for (int kx = 0; kx < 3; ++kx) {
        int tap = ky * 3 + kx;
        int toff = (ky * 18 + kx) * XS_STRIDE;
        half8 Ah[4], Al[4];
#pragma unroll
        for (int g = 0; g < 4; ++g) {
          Ah[g] = *(const half8*)(xhi + abase[g] + toff);
          Al[g] = *(const half8*)(xlo + abase[g] + toff);
        }
#pragma unroll
        for (int nt = 0; nt < 2; ++nt) {
          int fid = (((tap * 16 + icb) * 32 + (ntblk << 1) + nt) << 1);
          half8 Bh = B8[(size_t)fid * 64 + lane];
          half8 Bl = B8[(size_t)(fid + 1) * 64 + lane];
#pragma unroll
          for (int g = 0; g < 4; ++g) {
            acc0[g][nt] = __builtin_amdgcn_mfma_f32_16x16x32_f16(Ah[g], Bh, acc0[g][nt], 0, 0, 0);
            accC[g][nt] = __builtin_amdgcn_mfma_f32_16x16x32_f16(Ah[g], Bl, accC[g][nt], 0, 0, 0);
            accC[g][nt] = __builtin_amdgcn_mfma_f32_16x16x32_f16(Al[g], Bh, accC[g][nt], 0, 0, 0);
          }
        }
      }
    }
  }
  // epilogue: C/D col=lane&15 (oc), row=quad*4+reg (spatial col) -> coalesced float4
#pragma unroll
  for (int g = 0; g < 4; ++g) {
#pragma unroll
    for (int nt = 0; nt < 2; ++nt) {
      int oc = (ntblk << 5) + (nt << 4) + col;
      float bv = bias[oc];
      int gy = ty0 + 4 * wv + g;
      int gx0 = tx0 + (quad << 2);
      f32x4 a0 = acc0[g][nt];
      f32x4 ac = accC[g][nt];
      float4 o;
      o.x = fmaf(ac.x, INV_LS, a0.x) * INV_WS + bv; o.x = o.x > 0.f ? o.x : 0.f;
      o.y = fmaf(ac.y, INV_LS, a0.y) * INV_WS + bv; o.y = o.y > 0.f ? o.y : 0.f;
      o.z = fmaf(ac.z, INV_LS, a0.z) * INV_WS + bv; o.z = o.z > 0.f ? o.z : 0.f;
      o.w = fmaf(ac.w, INV_LS, a0.w) * INV_WS + bv; o.w = o.w > 0.f ? o.w : 0.f;
      *(float4*)(h + ((size_t)img * CIN + oc) * HW + (gy << 6) + gx0) = o;
    }
  }
}

// ---------------- K2: 1x1 heads + transpose + fg + box decode ----------------
__global__ __launch_bounds__(256) void heads_kernel(
    const float* __restrict__ h, const float* __restrict__ sw,
    const float* __restrict__ sb, const float* __restrict__ lw,
    const float* __restrict__ lb, float* __restrict__ out,
    float* __restrict__ fgm, float* __restrict__ boxes) {
  __shared__ float wlds[2][64][56];
  __shared__ float part[128][56];
  int tid = threadIdx.x;
  int sl = tid >> 7;
  int pl = tid & 127;
  int blk = blockIdx.x;
  int n = blk >> 5;
  int s0 = (blk & 31) * 128;

  float acc[54];
#pragma unroll
  for (int k = 0; k < 54; k++) acc[k] = 0.f;

  for (int cc = 0; cc < 256; cc += 64) {
    for (int l = tid; l < 2 * 64 * 54; l += 256) {
      int slc = l / (64 * 54); int rem = l - slc * 64 * 54;
      int cl = rem / 54; int k = rem - cl * 54;
      int c = slc * 256 + cc + cl;
      wlds[slc][cl][k] = (k < 18) ? sw[k * CIN + c] : lw[(k - 18) * CIN + c];
    }
    __syncthreads();
    int cbase = sl * 256 + cc;
    for (int cl = 0; cl < 64; ++cl) {
      float hv = h[((size_t)n * CIN + cbase + cl) * HW + s0 + pl];
#pragma unroll
      for (int k = 0; k < 54; ++k) acc[k] = fmaf(hv, wlds[sl][cl][k], acc[k]);
    }
    __syncthreads();
  }
  if (sl == 1) {
#pragma unroll
    for (int k = 0; k < 54; k++) part[pl][k] = acc[k];
  }
  __syncthreads();
  if (sl == 0) {
#pragma unroll
    for (int k = 0; k < 54; k++) acc[k] += part[pl][k];
    int s = s0 + pl;
    int y = s >> 6, xx = s & 63;
    float sc[18], lo[36];
#pragma unroll
    for (int k = 0; k < 18; k++) sc[k] = acc[k] + sb[k];
#pragma unroll
    for (int k = 0; k < 36; k++) lo[k] = acc[18 + k] + lb[k];
    size_t base = (size_t)n * NANC + (size_t)s * 9;
#pragma unroll
    for (int i = 0; i < 36; i++) out[OUT_LOCS + base * 4 + i] = lo[i];
#pragma unroll
    for (int i = 0; i < 18; i++) out[OUT_SCORES + base * 2 + i] = sc[i];
    float syf = (float)(y * 16), sxf = (float)(xx * 16);
#pragma unroll
    for (int a = 0; a < 9; a++) {
      float s0v = sc[a * 2], s1v = sc[a * 2 + 1];
      float m = fmaxf(s0v, s1v);
      float e0 = expf(s0v - m), e1 = expf(s1v - m);
      float fg = e1 / (e0 + e1);
      int ri = a / 3, si = a - ri * 3;
      double r = (ri == 0) ? 0.5 : (ri == 1 ? 1.0 : 2.0);
      double scd = (si == 0) ? 8.0 : (si == 1 ? 16.0 : 32.0);
      double hhd = 16.0 * scd * sqrt(r);
      double wwd = 16.0 * scd * sqrt(1.0 / r);
      float a0 = (float)(8.0 - hhd * 0.5) + syf;
      float a1 = (float)(8.0 - wwd * 0.5) + sxf;
      float a2 = (float)(8.0 + hhd * 0.5) + syf;
      float a3 = (float)(8.0 + wwd * 0.5) + sxf;
      float hA = a2 - a0, wA = a3 - a1;
      float cy = a0 + 0.5f * hA, cx = a1 + 0.5f * wA;
      float dy = lo[a * 4 + 0], dx = lo[a * 4 + 1];
      float dh = lo[a * 4 + 2], dw = lo[a * 4 + 3];
      float cy2 = dy * hA + cy, cx2 = dx * wA + cx;
      float h2 = expf(dh) * hA, w2 = expf(dw) * wA;
      float b0 = cy2 - 0.5f * h2, b1 = cx2 - 0.5f * w2;
      float b2 = cy2 + 0.5f * h2, b3 = cx2 + 0.5f * w2;
      b0 = fminf(fmaxf(b0, 0.f), 1024.f);
      b1 = fminf(fmaxf(b1, 0.f), 1024.f);
      b2 = fminf(fmaxf(b2, 0.f), 1024.f);
      b3 = fminf(fmaxf(b3, 0.f), 1024.f);
      float hs = b2 - b0, wss = b3 - b1;
      bool valid = (hs >= 16.f) && (wss >= 16.f);
      size_t bi = base + a;
      boxes[bi * 4 + 0] = b0; boxes[bi * 4 + 1] = b1;
      boxes[bi * 4 + 2] = b2; boxes[bi * 4 + 3] = b3;
      fgm[bi] = valid ? fg : -__builtin_inff();
    }
  }
}

// ---------------- K3: top-2000 (4-pass radix on 32-bit orderable score) ----------------
__device__ __forceinline__ uint32_t ord32(float v) {
  uint32_t s = __float_as_uint(v);
  return (s & 0x80000000u) ? ~s : (s | 0x80000000u);
}

__global__ __launch_bounds__(1024) void select2_kernel(
    const float* __restrict__ fgm, const float* __restrict__ boxes,
    float4* __restrict__ selb, uint8_t* __restrict__ selv) {
  int n = blockIdx.x;
  const float* f = fgm + (size_t)n * NANC;
  __shared__ uint32_t hist[256];
  __shared__ uint32_t segsum[16], segsufE[16];
  __shared__ uint64_t keys[2048];
  __shared__ uint32_t sh_digit, sh_T, scnt;
  int tid = threadIdx.x;
  uint32_t pref = 0;
  uint32_t T = PRE;
  for (int p = 0; p < 4; ++p) {
    int shift = 24 - 8 * p;
    if (tid < 256) hist[tid] = 0;
    __syncthreads();
    for (int i = tid; i < NANC; i += 1024) {
      uint32_t u = ord32(f[i]);
      bool match = (p == 0) || ((u >> (shift + 8)) == (pref >> (shift + 8)));
      if (match) atomicAdd(&hist[(u >> shift) & 255u], 1u);
    }
    __syncthreads();
    if (tid < 16) {
      uint32_t s = 0;
      for (int j = 0; j < 16; ++j) s += hist[tid * 16 + j];
      segsum[tid] = s;
    }
    __syncthreads();
    if (tid == 0) {
      uint32_t run = 0;
      for (int s = 15; s >= 0; --s) { segsufE[s] = run; run += segsum[s]; }
    }
    __syncthreads();
    if (tid < 256) {
      int d = tid, s = d >> 4;
      uint32_t loc = 0;
      for (int j = d; j < (s + 1) * 16; ++j) loc += hist[j];
      uint32_t suf = segsufE[s] + loc;
      uint32_t sufn = suf - hist[d];
      if (suf >= T && sufn < T) { sh_digit = (uint32_t)d; sh_T = T - sufn; }
    }
    __syncthreads();
    pref |= sh_digit << shift;
    T = sh_T;
    __syncthreads();
  }
  if (tid == 0) scnt = 0;
  __syncthreads();
  for (int i = tid; i < NANC; i += 1024) {
    uint32_t u = ord32(f[i]);
    if (u >= pref) {
      uint32_t pos = atomicAdd(&scnt, 1u);
      if (pos < 2048) keys[pos] = ((uint64_t)u << 32) | (uint32_t)(~(uint32_t)i);
    }
  }
  __syncthreads();
  uint32_t sc = scnt > 2048 ? 2048 : scnt;
  for (int i = sc + tid; i < 2048; i += 1024) keys[i] = 0;
  __syncthreads();
  for (int k = 2; k <= 2048; k <<= 1) {
    for (int j = k >> 1; j > 0; j >>= 1) {
      for (int e = tid; e < 2048; e += 1024) {
        int partner = e ^ j;
        if (partner > e) {
          bool up = ((e & k) == 0);
          uint64_t a = keys[e], b = keys[partner];
          if (up ? (a < b) : (a > b)) { keys[e] = b; keys[partner] = a; }
        }
      }
      __syncthreads();
    }
  }
  for (int t2 = tid; t2 < PRE; t2 += 1024) {
    uint64_t key = keys[t2];
    uint32_t idx = ~((uint32_t)(key & 0xFFFFFFFFu));
    const float4* bp = (const float4*)(boxes + ((size_t)n * NANC + idx) * 4);
    selb[(size_t)n * 2048 + t2] = *bp;
    selv[(size_t)n * 2048 + t2] = ((uint32_t)(key >> 32)) > 0x007FFFFFu ? 1 : 0;
  }
}

// ---------------- K4a: NMS suppression mask (grid-parallel) ----------------
__global__ __launch_bounds__(256) void nms_mask_kernel(
    const float4* __restrict__ selb, uint64_t* __restrict__ mask) {
  __shared__ float by0[PRE], bx0_[PRE], by1[PRE], bx1_[PRE], bar[PRE];
  int b = blockIdx.x;
  int n = b / 250;
  int i0 = (b % 250) * 8;
  int tid = threadIdx.x;
  for (int j = tid; j < PRE; j += 256) {
    float4 bb = selb[(size_t)n * 2048 + j];
    by0[j] = bb.x; bx0_[j] = bb.y; by1[j] = bb.z; bx1_[j] = bb.w;
    bar[j] = (bb.z - bb.x) * (bb.w - bb.y);
  }
  __syncthreads();
  int i = i0 + (tid >> 5);
  int jw = tid & 31;
  float iy0 = by0[i], ix0 = bx0_[i], iy1 = by1[i], ix1 = bx1_[i], ia = bar[i];
  uint64_t bits = 0;
  int jb = jw * 64;
  for (int tb = 0; tb < 64; ++tb) {
    int tbp = (tb + jw) & 63;
    int j = jb + tbp;
    if (j < PRE && j > i) {
      float ty = fmaxf(iy0, by0[j]);
      float txx = fmaxf(ix0, bx0_[j]);
      float byv = fminf(iy1, by1[j]);
      float bxv = fminf(ix1, bx1_[j]);
      float ih = byv - ty; if (ih < 0.f) ih = 0.f;
      float iw = bxv - txx; if (iw < 0.f) iw = 0.f;
      float inter = ih * iw;
      float iou = inter / (ia + bar[j] - inter + 1e-9f);
      if (iou > 0.7f) bits |= (1ull << tbp);
    }
  }
  mask[((size_t)n * PRE + i) * 32 + jw] = bits;
}

// ---------------- K4b: serial bit-scan NMS + write rois (1 wave / image) ----------------
__global__ __launch_bounds__(64) void nms_scan_kernel(
    const uint8_t* __restrict__ selv, const uint64_t* __restrict__ mask,
    const float4* __restrict__ selb, float* __restrict__ out) {
  int n = blockIdx.x;
  int lane = threadIdx.x;
  const uint8_t* sv = selv + (size_t)n * 2048;
  uint64_t kw = 0;
  for (int wblk = 0; wblk < 32; ++wblk) {
    int j = wblk * 64 + lane;
    bool pred = (j < PRE) && (sv[j] != 0);
    uint64_t m = __ballot(pred);
    if (lane == wblk) kw = m;
  }
  const uint64_t* mrow = mask + (size_t)n * PRE * 32;
  for (int i0 = 0; i0 < PRE; i0 += 16) {
    uint64_t rr[16];
#pragma unroll
    for (int tt = 0; tt < 16; ++tt)
      rr[tt] = (lane < 32) ? mrow[(size_t)(i0 + tt) * 32 + lane] : 0;
#pragma unroll
    for (int tt = 0; tt < 16; ++tt) {
      int i = i0 + tt;
      uint64_t w = __shfl(kw, i >> 6);
      if ((w >> (i & 63)) & 1ull) kw &= ~rr[tt];
    }
  }
  uint64_t kwv = (lane < 32) ? kw : 0ull;
  int pc = __popcll(kwv);
  int pre = pc;
  for (int d = 1; d < 64; d <<= 1) {
    int v = __shfl_up(pre, d);
    if (lane >= d) pre += v;
  }
  int total = __shfl(pre, 63);
  int rank = pre - pc;
  uint64_t bits = kwv;
  while (bits) {
    int bpos = __ffsll((unsigned long long)bits) - 1;
    bits &= bits - 1;
    if (rank < POST) {
      int j = lane * 64 + bpos;
      float4 bx = selb[(size_t)n * 2048 + j];
      size_t o = (size_t)OUT_ROIS + ((size_t)n * POST + rank) * 4;
      out[o + 0] = bx.x; out[o + 1] = bx.y; out[o + 2] = bx.z; out[o + 3] = bx.w;
    }
    rank++;
  }
  int cnt = total > POST ? POST : total;
  for (int r2 = cnt + lane; r2 < POST; r2 += 64) {
    size_t o = (size_t)OUT_ROIS + ((size_t)n * POST + r2) * 4;
    out[o + 0] = 0.f; out[o + 1] = 0.f; out[o + 2] = 0.f; out[o + 3] = 0.f;
  }
  for (int r2 = lane; r2 < POST; r2 += 64)
    out[OUT_RIDX + n * POST + r2] = (float)n;
}

extern "C" void kernel_launch(void* const* d_in, const int* in_sizes, int n_in,
                              void* d_out, int out_size, void* d_ws, size_t ws_size,
                              hipStream_t stream) {
  const float* x   = (const float*)d_in[0];
  const float* c1w = (const float*)d_in[1];
  const float* c1b = (const float*)d_in[2];
  const float* sw  = (const float*)d_in[3];
  const float* sb  = (const float*)d_in[4];
  const float* lw  = (const float*)d_in[5];
  const float* lb  = (const float*)d_in[6];
  float* out = (float*)d_out;
  char* ws = (char*)d_ws;
  float*     hbuf = (float*)(ws);                        // 67,108,864 B
  float*     fgm  = (float*)(ws + 67108864);             // 1,179,648 B
  float*     boxes= (float*)(ws + 68288512);             // 4,718,592 B
  _Float16*  Bf   = (_Float16*)(ws + 73007104);          // 9,437,184 B (4,718,592 f16)
  float4*    selb = (float4*)(ws + 82444288);            // 262,144 B
  uint8_t*   selv = (uint8_t*)(ws + 82706432);           // 16,384 B
  uint64_t*  mask = (uint64_t*)(ws + 82722816);          // 4,096,000 B

  anchor_kernel<<<144, 256, 0, stream>>>(out);
  wprep_kernel<<<18432, 256, 0, stream>>>(c1w, Bf);
  conv3_mfma<<<2048, 256, 0, stream>>>(x, Bf, c1b, hbuf);
  heads_kernel<<<256, 256, 0, stream>>>(hbuf, sw, sb, lw, lb, out, fgm, boxes);
  select2_kernel<<<8, 1024, 0, stream>>>(fgm, boxes, selb, selv);
  nms_mask_kernel<<<2000, 256, 0, stream>>>(selb, mask);
  nms_scan_kernel<<<8, 64, 0, stream>>>(selv, mask, selb, out);
}

// Round 9
// 960.399 us; speedup vs baseline: 4.4481x; 1.6584x over previous
//
#include <hip/hip_runtime.h>
#include <math.h>
#include <stdint.h>

#define NB 8
#define CIN 512
#define HW 4096
#define ANUM 9
#define NANC 36864
#define PRE 2000
#define POST 300

// d_out float offsets
#define OUT_LOCS   0
#define OUT_SCORES 1179648
#define OUT_ROIS   1769472
#define OUT_RIDX   1779072
#define OUT_ANC    1781472

typedef _Float16 half8 __attribute__((ext_vector_type(8)));
typedef float f32x4 __attribute__((ext_vector_type(4)));

#define WSCALE 256.0f
#define LSCALE 4096.0f
#define INV_WS (1.0f / 256.0f)
#define INV_LS (1.0f / 4096.0f)
#define XS_STRIDE 40  // halfs per halo position (32 data + 8 pad): b128 reads conflict-free

// ---------------- K0: anchors ----------------
__global__ void anchor_kernel(float* __restrict__ out) {
  int i = blockIdx.x * 256 + threadIdx.x;
  if (i >= NANC) return;
  int s = i / 9, a = i - s * 9;
  int y = s >> 6, x = s & 63;
  int ri = a / 3, si = a - ri * 3;
  double r = (ri == 0) ? 0.5 : (ri == 1 ? 1.0 : 2.0);
  double sc = (si == 0) ? 8.0 : (si == 1 ? 16.0 : 32.0);
  double hh = 16.0 * sc * sqrt(r);
  double ww = 16.0 * sc * sqrt(1.0 / r);
  float a0 = (float)(8.0 - hh * 0.5);
  float a1 = (float)(8.0 - ww * 0.5);
  float a2 = (float)(8.0 + hh * 0.5);
  float a3 = (float)(8.0 + ww * 0.5);
  float sy = (float)(y * 16), sx = (float)(x * 16);
  out[OUT_ANC + i * 4 + 0] = a0 + sy;
  out[OUT_ANC + i * 4 + 1] = a1 + sx;
  out[OUT_ANC + i * 4 + 2] = a2 + sy;
  out[OUT_ANC + i * 4 + 3] = a3 + sx;
}

// ---------------- K0b: weight limb-split into B-fragment layout (unchanged) ----------------
// frag id = (((tap*16 + icb)*32 + ob16)*2 + limb); elem = fid*512 + lane*8 + j
__global__ void wprep_kernel(const float* __restrict__ w, _Float16* __restrict__ Bf) {
  int i = blockIdx.x * 256 + threadIdx.x;  // < 4718592
  int j = i & 7;
  int l = (i >> 3) & 63;
  int limb = (i >> 9) & 1;
  int ob = (i >> 10) & 31;
  int icb = (i >> 15) & 15;
  int tap = i >> 19;
  int ic = icb * 32 + ((l >> 4) << 3) + j;
  int oc = (ob << 4) + (l & 15);
  float v = w[((size_t)oc * CIN + ic) * 9 + tap] * WSCALE;
  _Float16 hi = (_Float16)v;
  Bf[i] = limb ? (_Float16)((v - (float)hi) * LSCALE) : hi;
}

// ---------------- K1: conv3x3 + bias + relu via MFMA (scaled f16 limbs) ----------------
// v3b: same as R8 but with the B-group stride fixed (<<12: one (tap,icb) group =
// 32 ob16 x 2 limbs x 64 half8 = 4096 half8s; R8's <<11 read scrambled weights).
__global__ __launch_bounds__(256) void conv3_mfma(
    const float* __restrict__ x, const _Float16* __restrict__ Bf,
    const float* __restrict__ bias, float* __restrict__ h) {
  __shared__ _Float16 xhi[108 * XS_STRIDE];  // 8640 B
  __shared__ _Float16 xlo[108 * XS_STRIDE];  // 8640 B
  int blk = blockIdx.x;
  int ntblk = blk & 3;
  int mb = blk >> 2;
  int img = mb >> 6;
  int t = mb & 63;
  int ty0 = (t >> 2) * 4, tx0 = (t & 3) * 16;
  int tid = threadIdx.x;
  int wv = tid >> 6, lane = tid & 63;
  int col = lane & 15, quad = lane >> 4;

  f32x4 acc0[4][2], accC[4][2];
#pragma unroll
  for (int g = 0; g < 4; ++g)
#pragma unroll
    for (int nt = 0; nt < 2; ++nt) {
      acc0[g][nt] = (f32x4){0.f, 0.f, 0.f, 0.f};
      accC[g][nt] = (f32x4){0.f, 0.f, 0.f, 0.f};
    }

  // hoisted staging addresses: 864 slots = 108 pos x 8 icg, 4 per thread
  int goffs[4];   // icg*16384 + gy*64+gx, or -1 if OOB/inactive
  int laddr[4];   // pos*XS_STRIDE + icg*4, or -1 if inactive
#pragma unroll
  for (int s = 0; s < 4; ++s) {
    int l = tid + (s << 8);
    bool act = (l < 864);
    int icg = l / 108;
    int pos = l - icg * 108;
    int py = pos / 18, px = pos - py * 18;
    int gy = ty0 - 1 + py, gx = tx0 - 1 + px;
    bool inb = act && ((unsigned)gy < 64u) && ((unsigned)gx < 64u);
    goffs[s] = inb ? ((icg << 14) + (gy << 6) + gx) : -1;
    laddr[s] = act ? (pos * XS_STRIDE + (icg << 2)) : -1;
  }

  const float* xn = x + ((size_t)img << 21);  // img*512*4096
  const half8* B8 = (const half8*)Bf;
  // B-frag base for this wave's oc chunk: half8 index =
  //   (tap*16+icb)*4096 + ob16*128 + limb*64 + lane, ob16 = ntblk*8 + wv*2 + nt
  const half8* Bq = B8 + (((size_t)(ntblk * 8 + wv * 2)) << 7) + lane;
  int abase = col * XS_STRIDE + quad * 8;

#pragma unroll 1
  for (int icb = 0; icb < 16; ++icb) {
    __syncthreads();
    const float* xb = xn + ((size_t)icb << 17);  // icb*32*4096
#pragma unroll
    for (int s = 0; s < 4; ++s) {
      if (laddr[s] >= 0) {
        float v0 = 0.f, v1 = 0.f, v2 = 0.f, v3 = 0.f;
        if (goffs[s] >= 0) {
          const float* p = xb + goffs[s];
          v0 = p[0]; v1 = p[HW]; v2 = p[2 * HW]; v3 = p[3 * HW];
        }
        _Float16 h0 = (_Float16)v0, h1 = (_Float16)v1;
        _Float16 h2 = (_Float16)v2, h3 = (_Float16)v3;
        _Float16 e0 = (_Float16)((v0 - (float)h0) * LSCALE);
        _Float16 e1 = (_Float16)((v1 - (float)h1) * LSCALE);
        _Float16 e2 = (_Float16)((v2 - (float)h2) * LSCALE);
        _Float16 e3 = (_Float16)((v3 - (float)h3) * LSCALE);
        typedef _Float16 h4 __attribute__((ext_vector_type(4)));
        *(h4*)(xhi + laddr[s]) = (h4){h0, h1, h2, h3};
        *(h4*)(xlo + laddr[s]) = (h4){e0, e1, e2, e3};
      }
    }
    __syncthreads();
#pragma unroll
    for (int ky = 0; ky < 3; ++ky) {
#pragma unroll
      for (int kx = 0; kx < 3; ++kx) {
        int tap = ky * 3 + kx;
        size_t boff = ((size_t)(tap * 16 + icb)) << 12;  // 4096 half8 per (tap,icb)
        half8 Bh0 = Bq[boff];
        half8 Bl0 = Bq[boff + 64];
        half8 Bh1 = Bq[boff + 128];
        half8 Bl1 = Bq[boff + 192];
        int toff = (ky * 18 + kx) * XS_STRIDE + abase;
#pragma unroll
        for (int g = 0; g < 4; ++g) {
          int off = toff + g * (18 * XS_STRIDE);
          half8 Ah = *(const half8*)(xhi + off);
          half8 Al = *(const half8*)(xlo + off);
          acc0[g][0] = __builtin_amdgcn_mfma_f32_16x16x32_f16(Ah, Bh0, acc0[g][0], 0, 0, 0);
          accC[g][0] = __builtin_amdgcn_mfma_f32_16x16x32_f16(Ah, Bl0, accC[g][0], 0, 0, 0);
          accC[g][0] = __builtin_amdgcn_mfma_f32_16x16x32_f16(Al, Bh0, accC[g][0], 0, 0, 0);
          acc0[g][1] = __builtin_amdgcn_mfma_f32_16x16x32_f16(Ah, Bh1, acc0[g][1], 0, 0, 0);
          accC[g][1] = __builtin_amdgcn_mfma_f32_16x16x32_f16(Ah, Bl1, accC[g][1], 0, 0, 0);
          accC[g][1] = __builtin_amdgcn_mfma_f32_16x16x32_f16(Al, Bh1, accC[g][1], 0, 0, 0);
        }
      }
    }
  }
  // epilogue: C/D col=lane&15 (oc), row=quad*4+reg (px col) -> float4 store
#pragma unroll
  for (int g = 0; g < 4; ++g) {
#pragma unroll
    for (int nt = 0; nt < 2; ++nt) {
      int oc = (ntblk << 7) + (wv << 5) + (nt << 4) + col;
      float bv = bias[oc];
      int gy = ty0 + g;
      int gx0 = tx0 + (quad << 2);
      f32x4 a0 = acc0[g][nt];
      f32x4 ac = accC[g][nt];
      float4 o;
      o.x = fmaf(ac.x, INV_LS, a0.x) * INV_WS + bv; o.x = o.x > 0.f ? o.x : 0.f;
      o.y = fmaf(ac.y, INV_LS, a0.y) * INV_WS + bv; o.y = o.y > 0.f ? o.y : 0.f;
      o.z = fmaf(ac.z, INV_LS, a0.z) * INV_WS + bv; o.z = o.z > 0.f ? o.z : 0.f;
      o.w = fmaf(ac.w, INV_LS, a0.w) * INV_WS + bv; o.w = o.w > 0.f ? o.w : 0.f;
      *(float4*)(h + ((size_t)img * CIN + oc) * HW + (gy << 6) + gx0) = o;
    }
  }
}

// ---------------- K2: 1x1 heads + transpose + fg + box decode ----------------
__global__ __launch_bounds__(256) void heads_kernel(
    const float* __restrict__ h, const float* __restrict__ sw,
    const float* __restrict__ sb, const float* __restrict__ lw,
    const float* __restrict__ lb, float* __restrict__ out,
    float* __restrict__ fgm, float* __restrict__ boxes) {
  __shared__ float wlds[2][64][56];
  __shared__ float part[128][56];
  int tid = threadIdx.x;
  int sl = tid >> 7;
  int pl = tid & 127;
  int blk = blockIdx.x;
  int n = blk >> 5;
  int s0 = (blk & 31) * 128;

  float acc[54];
#pragma unroll
  for (int k = 0; k < 54; k++) acc[k] = 0.f;

  for (int cc = 0; cc < 256; cc += 64) {
    for (int l = tid; l < 2 * 64 * 54; l += 256) {
      int slc = l / (64 * 54); int rem = l - slc * 64 * 54;
      int cl = rem / 54; int k = rem - cl * 54;
      int c = slc * 256 + cc + cl;
      wlds[slc][cl][k] = (k < 18) ? sw[k * CIN + c] : lw[(k - 18) * CIN + c];
    }
    __syncthreads();
    int cbase = sl * 256 + cc;
#pragma unroll 4
    for (int cl = 0; cl < 64; ++cl) {
      float hv = h[((size_t)n * CIN + cbase + cl) * HW + s0 + pl];
#pragma unroll
      for (int k = 0; k < 54; ++k) acc[k] = fmaf(hv, wlds[sl][cl][k], acc[k]);
    }
    __syncthreads();
  }
  if (sl == 1) {
#pragma unroll
    for (int k = 0; k < 54; k++) part[pl][k] = acc[k];
  }
  __syncthreads();
  if (sl == 0) {
#pragma unroll
    for (int k = 0; k < 54; k++) acc[k] += part[pl][k];
    int s = s0 + pl;
    int y = s >> 6, xx = s & 63;
    float sc[18], lo[36];
#pragma unroll
    for (int k = 0; k < 18; k++) sc[k] = acc[k] + sb[k];
#pragma unroll
    for (int k = 0; k < 36; k++) lo[k] = acc[18 + k] + lb[k];
    size_t base = (size_t)n * NANC + (size_t)s * 9;
#pragma unroll
    for (int i = 0; i < 36; i++) out[OUT_LOCS + base * 4 + i] = lo[i];
#pragma unroll
    for (int i = 0; i < 18; i++) out[OUT_SCORES + base * 2 + i] = sc[i];
    float syf = (float)(y * 16), sxf = (float)(xx * 16);
#pragma unroll
    for (int a = 0; a < 9; a++) {
      float s0v = sc[a * 2], s1v = sc[a * 2 + 1];
      float m = fmaxf(s0v, s1v);
      float e0 = expf(s0v - m), e1 = expf(s1v - m);
      float fg = e1 / (e0 + e1);
      int ri = a / 3, si = a - ri * 3;
      double r = (ri == 0) ? 0.5 : (ri == 1 ? 1.0 : 2.0);
      double scd = (si == 0) ? 8.0 : (si == 1 ? 16.0 : 32.0);
      double hhd = 16.0 * scd * sqrt(r);
      double wwd = 16.0 * scd * sqrt(1.0 / r);
      float a0 = (float)(8.0 - hhd * 0.5) + syf;
      float a1 = (float)(8.0 - wwd * 0.5) + sxf;
      float a2 = (float)(8.0 + hhd * 0.5) + syf;
      float a3 = (float)(8.0 + wwd * 0.5) + sxf;
      float hA = a2 - a0, wA = a3 - a1;
      float cy = a0 + 0.5f * hA, cx = a1 + 0.5f * wA;
      float dy = lo[a * 4 + 0], dx = lo[a * 4 + 1];
      float dh = lo[a * 4 + 2], dw = lo[a * 4 + 3];
      float cy2 = dy * hA + cy, cx2 = dx * wA + cx;
      float h2 = expf(dh) * hA, w2 = expf(dw) * wA;
      float b0 = cy2 - 0.5f * h2, b1 = cx2 - 0.5f * w2;
      float b2 = cy2 + 0.5f * h2, b3 = cx2 + 0.5f * w2;
      b0 = fminf(fmaxf(b0, 0.f), 1024.f);
      b1 = fminf(fmaxf(b1, 0.f), 1024.f);
      b2 = fminf(fmaxf(b2, 0.f), 1024.f);
      b3 = fminf(fmaxf(b3, 0.f), 1024.f);
      float hs = b2 - b0, wss = b3 - b1;
      bool valid = (hs >= 16.f) && (wss >= 16.f);
      size_t bi = base + a;
      boxes[bi * 4 + 0] = b0; boxes[bi * 4 + 1] = b1;
      boxes[bi * 4 + 2] = b2; boxes[bi * 4 + 3] = b3;
      fgm[bi] = valid ? fg : -__builtin_inff();
    }
  }
}

// ---------------- K3: top-2000 (4-pass radix on 32-bit orderable score) ----------------
__device__ __forceinline__ uint32_t ord32(float v) {
  uint32_t s = __float_as_uint(v);
  return (s & 0x80000000u) ? ~s : (s | 0x80000000u);
}

__global__ __launch_bounds__(1024) void select2_kernel(
    const float* __restrict__ fgm, const float* __restrict__ boxes,
    float4* __restrict__ selb, uint8_t* __restrict__ selv) {
  int n = blockIdx.x;
  const float* f = fgm + (size_t)n * NANC;
  __shared__ uint32_t hist[256];
  __shared__ uint32_t segsum[16], segsufE[16];
  __shared__ uint64_t keys[2048];
  __shared__ uint32_t sh_digit, sh_T, scnt;
  int tid = threadIdx.x;
  uint32_t pref = 0;
  uint32_t T = PRE;
  for (int p = 0; p < 4; ++p) {
    int shift = 24 - 8 * p;
    if (tid < 256) hist[tid] = 0;
    __syncthreads();
    for (int i = tid; i < NANC; i += 1024) {
      uint32_t u = ord32(f[i]);
      bool match = (p == 0) || ((u >> (shift + 8)) == (pref >> (shift + 8)));
      if (match) atomicAdd(&hist[(u >> shift) & 255u], 1u);
    }
    __syncthreads();
    if (tid < 16) {
      uint32_t s = 0;
      for (int j = 0; j < 16; ++j) s += hist[tid * 16 + j];
      segsum[tid] = s;
    }
    __syncthreads();
    if (tid == 0) {
      uint32_t run = 0;
      for (int s = 15; s >= 0; --s) { segsufE[s] = run; run += segsum[s]; }
    }
    __syncthreads();
    if (tid < 256) {
      int d = tid, s = d >> 4;
      uint32_t loc = 0;
      for (int j = d; j < (s + 1) * 16; ++j) loc += hist[j];
      uint32_t suf = segsufE[s] + loc;
      uint32_t sufn = suf - hist[d];
      if (suf >= T && sufn < T) { sh_digit = (uint32_t)d; sh_T = T - sufn; }
    }
    __syncthreads();
    pref |= sh_digit << shift;
    T = sh_T;
    __syncthreads();
  }
  if (tid == 0) scnt = 0;
  __syncthreads();
  for (int i = tid; i < NANC; i += 1024) {
    uint32_t u = ord32(f[i]);
    if (u >= pref) {
      uint32_t pos = atomicAdd(&scnt, 1u);
      if (pos < 2048) keys[pos] = ((uint64_t)u << 32) | (uint32_t)(~(uint32_t)i);
    }
  }
  __syncthreads();
  uint32_t sc = scnt > 2048 ? 2048 : scnt;
  for (int i = sc + tid; i < 2048; i += 1024) keys[i] = 0;
  __syncthreads();
  for (int k = 2; k <= 2048; k <<= 1) {
    for (int j = k >> 1; j > 0; j >>= 1) {
      for (int e = tid; e < 2048; e += 1024) {
        int partner = e ^ j;
        if (partner > e) {
          bool up = ((e & k) == 0);
          uint64_t a = keys[e], b = keys[partner];
          if (up ? (a < b) : (a > b)) { keys[e] = b; keys[partner] = a; }
        }
      }
      __syncthreads();
    }
  }
  for (int t2 = tid; t2 < PRE; t2 += 1024) {
    uint64_t key = keys[t2];
    uint32_t idx = ~((uint32_t)(key & 0xFFFFFFFFu));
    const float4* bp = (const float4*)(boxes + ((size_t)n * NANC + idx) * 4);
    selb[(size_t)n * 2048 + t2] = *bp;
    selv[(size_t)n * 2048 + t2] = ((uint32_t)(key >> 32)) > 0x007FFFFFu ? 1 : 0;
  }
}

// ---------------- K4a: NMS suppression mask (grid-parallel) ----------------
__global__ __launch_bounds__(256) void nms_mask_kernel(
    const float4* __restrict__ selb, uint64_t* __restrict__ mask) {
  __shared__ float by0[PRE], bx0_[PRE], by1[PRE], bx1_[PRE], bar[PRE];
  int b = blockIdx.x;
  int n = b / 250;
  int i0 = (b % 250) * 8;
  int tid = threadIdx.x;
  for (int j = tid; j < PRE; j += 256) {
    float4 bb = selb[(size_t)n * 2048 + j];
    by0[j] = bb.x; bx0_[j] = bb.y; by1[j] = bb.z; bx1_[j] = bb.w;
    bar[j] = (bb.z - bb.x) * (bb.w - bb.y);
  }
  __syncthreads();
  int i = i0 + (tid >> 5);
  int jw = tid & 31;
  float iy0 = by0[i], ix0 = bx0_[i], iy1 = by1[i], ix1 = bx1_[i], ia = bar[i];
  uint64_t bits = 0;
  int jb = jw * 64;
  for (int tb = 0; tb < 64; ++tb) {
    int tbp = (tb + jw) & 63;
    int j = jb + tbp;
    if (j < PRE && j > i) {
      float ty = fmaxf(iy0, by0[j]);
      float txx = fmaxf(ix0, bx0_[j]);
      float byv = fminf(iy1, by1[j]);
      float bxv = fminf(ix1, bx1_[j]);
      float ih = byv - ty; if (ih < 0.f) ih = 0.f;
      float iw = bxv - txx; if (iw < 0.f) iw = 0.f;
      float inter = ih * iw;
      float iou = inter / (ia + bar[j] - inter + 1e-9f);
      if (iou > 0.7f) bits |= (1ull << tbp);
    }
  }
  mask[((size_t)n * PRE + i) * 32 + jw] = bits;
}

// ---------------- K4b: serial bit-scan NMS + write rois (1 wave / image) ----------------
// Early-exit: once POST kept boxes found at index i*, later rows cannot change output.
__global__ __launch_bounds__(64) void nms_scan_kernel(
    const uint8_t* __restrict__ selv, const uint64_t* __restrict__ mask,
    const float4* __restrict__ selb, float* __restrict__ out) {
  int n = blockIdx.x;
  int lane = threadIdx.x;
  const uint8_t* sv = selv + (size_t)n * 2048;
  uint64_t kw = 0;
  for (int wblk = 0; wblk < 32; ++wblk) {
    int j = wblk * 64 + lane;
    bool pred = (j < PRE) && (sv[j] != 0);
    uint64_t m = __ballot(pred);
    if (lane == wblk) kw = m;
  }
  const uint64_t* mrow = mask + (size_t)n * PRE * 32;
  int istar = PRE - 1;
  int csf = 0;
  bool done = false;
  for (int i0 = 0; i0 < PRE && !done; i0 += 16) {
    uint64_t rr[16];
#pragma unroll
    for (int tt = 0; tt < 16; ++tt)
      rr[tt] = (lane < 32) ? mrow[(size_t)(i0 + tt) * 32 + lane] : 0;
#pragma unroll
    for (int tt = 0; tt < 16; ++tt) {
      int i = i0 + tt;
      uint64_t w = __shfl(kw, i >> 6);
      if ((w >> (i & 63)) & 1ull) {
        kw &= ~rr[tt];
        csf++;
        if (csf >= POST) { istar = i; done = true; break; }
      }
    }
  }
  // mask off indices beyond istar
  int wordi = istar >> 6, biti = istar & 63;
  uint64_t km = (lane < wordi) ? ~0ull
              : (lane == wordi ? ((biti == 63) ? ~0ull : ((1ull << (biti + 1)) - 1ull)) : 0ull);
  uint64_t kwv = (lane < 32) ? (kw & km) : 0ull;
  int pc = __popcll(kwv);
  int pre = pc;
  for (int d = 1; d < 64; d <<= 1) {
    int v = __shfl_up(pre, d);
    if (lane >= d) pre += v;
  }
  int total = __shfl(pre, 63);
  int rank = pre - pc;
  uint64_t bits = kwv;
  while (bits) {
    int bpos = __ffsll((unsigned long long)bits) - 1;
    bits &= bits - 1;
    if (rank < POST) {
      int j = lane * 64 + bpos;
      float4 bx = selb[(size_t)n * 2048 + j];
      size_t o = (size_t)OUT_ROIS + ((size_t)n * POST + rank) * 4;
      out[o + 0] = bx.x; out[o + 1] = bx.y; out[o + 2] = bx.z; out[o + 3] = bx.w;
    }
    rank++;
  }
  int cnt = total > POST ? POST : total;
  for (int r2 = cnt + lane; r2 < POST; r2 += 64) {
    size_t o = (size_t)OUT_ROIS + ((size_t)n * POST + r2) * 4;
    out[o + 0] = 0.f; out[o + 1] = 0.f; out[o + 2] = 0.f; out[o + 3] = 0.f;
  }
  for (int r2 = lane; r2 < POST; r2 += 64)
    out[OUT_RIDX + n * POST + r2] = (float)n;
}

extern "C" void kernel_launch(void* const* d_in, const int* in_sizes, int n_in,
                              void* d_out, int out_size, void* d_ws, size_t ws_size,
                              hipStream_t stream) {
  const float* x   = (const float*)d_in[0];
  const float* c1w = (const float*)d_in[1];
  const float* c1b = (const float*)d_in[2];
  const float* sw  = (const float*)d_in[3];
  const float* sb  = (const float*)d_in[4];
  const float* lw  = (const float*)d_in[5];
  const float* lb  = (const float*)d_in[6];
  float* out = (float*)d_out;
  char* ws = (char*)d_ws;
  float*     hbuf = (float*)(ws);                        // 67,108,864 B
  float*     fgm  = (float*)(ws + 67108864);             // 1,179,648 B
  float*     boxes= (float*)(ws + 68288512);             // 4,718,592 B
  _Float16*  Bf   = (_Float16*)(ws + 73007104);          // 9,437,184 B
  float4*    selb = (float4*)(ws + 82444288);            // 262,144 B
  uint8_t*   selv = (uint8_t*)(ws + 82706432);           // 16,384 B
  uint64_t*  mask = (uint64_t*)(ws + 82722816);          // 4,096,000 B

  anchor_kernel<<<144, 256, 0, stream>>>(out);
  wprep_kernel<<<18432, 256, 0, stream>>>(c1w, Bf);
  conv3_mfma<<<2048, 256, 0, stream>>>(x, Bf, c1b, hbuf);
  heads_kernel<<<256, 256, 0, stream>>>(hbuf, sw, sb, lw, lb, out, fgm, boxes);
  select2_kernel<<<8, 1024, 0, stream>>>(fgm, boxes, selb, selv);
  nms_mask_kernel<<<2000, 256, 0, stream>>>(selb, mask);
  nms_scan_kernel<<<8, 64, 0, stream>>>(selv, mask, selb, out);
}